// Round 7
// baseline (401.333 us; speedup 1.0000x reference)
//
#include <hip/hip_runtime.h>

#define D 128
#define TILE 256

typedef __attribute__((ext_vector_type(8))) short short8;
typedef __attribute__((ext_vector_type(4))) float f32x4;

__device__ inline unsigned short f2bf(float f) {
    unsigned u = __float_as_uint(f);
    return (unsigned short)((u + 0x7FFFu + ((u >> 16) & 1u)) >> 16);
}
__device__ inline float bflo(unsigned u) { return __uint_as_float(u << 16); }
__device__ inline float bfhi(unsigned u) { return __uint_as_float(u & 0xFFFF0000u); }

// ---------------------------------------------------------------- deg init: col-deg=1 (self loop), row-cnt=0
__global__ __launch_bounds__(256) void k_deg_init(int* __restrict__ deg, int* __restrict__ rdeg, int n) {
    int i = blockIdx.x * 256 + threadIdx.x;
    if (i < n) { deg[i] = 1; rdeg[i] = 0; }
}

// ---------------------------------------------------------------- count by dest
__global__ __launch_bounds__(256) void k_count(const int* __restrict__ col, int* __restrict__ deg, int E) {
    int e = blockIdx.x * 256 + threadIdx.x;
    if (e < E) atomicAdd(&deg[col[e]], 1);
}

// ---------------------------------------------------------------- count by source
__global__ __launch_bounds__(256) void k_count_row(const int* __restrict__ row, int* __restrict__ rdeg, int E) {
    int e = blockIdx.x * 256 + threadIdx.x;
    if (e < E) atomicAdd(&rdeg[row[e]], 1);
}

// ---------------------------------------------------------------- scan phase 1 (dest: deg-1)
__global__ __launch_bounds__(TILE) void k_tilesum(const int* __restrict__ deg, int* __restrict__ tileSum, int n) {
    __shared__ int s[TILE];
    int t = threadIdx.x;
    int i = blockIdx.x * TILE + t;
    s[t] = (i < n) ? deg[i] - 1 : 0;
    __syncthreads();
    for (int off = TILE / 2; off > 0; off >>= 1) {
        if (t < off) s[t] += s[t + off];
        __syncthreads();
    }
    if (t == 0) tileSum[blockIdx.x] = s[0];
}

// ---------------------------------------------------------------- scan phase 1 (row: rdeg)
__global__ __launch_bounds__(TILE) void k_tilesum_r(const int* __restrict__ cnt, int* __restrict__ tileSum, int n) {
    __shared__ int s[TILE];
    int t = threadIdx.x;
    int i = blockIdx.x * TILE + t;
    s[t] = (i < n) ? cnt[i] : 0;
    __syncthreads();
    for (int off = TILE / 2; off > 0; off >>= 1) {
        if (t < off) s[t] += s[t + off];
        __syncthreads();
    }
    if (t == 0) tileSum[blockIdx.x] = s[0];
}

// ---------------------------------------------------------------- scan phase 2 (1 block)
__global__ __launch_bounds__(TILE) void k_tilescan(const int* __restrict__ tileSum, int* __restrict__ tileBase,
                                                   int* __restrict__ total_out, int nTiles) {
    __shared__ int s[TILE];
    int t = threadIdx.x;
    int v = (t < nTiles) ? tileSum[t] : 0;
    s[t] = v;
    __syncthreads();
    for (int off = 1; off < TILE; off <<= 1) {
        int tmp = (t >= off) ? s[t - off] : 0;
        __syncthreads();
        s[t] += tmp;
        __syncthreads();
    }
    if (t < nTiles) tileBase[t] = s[t] - v;
    if (t == TILE - 1) total_out[0] = s[TILE - 1];
}

// ---------------------------------------------------------------- scan phase 3 (dest: offsets+cursor+dinv)
__global__ __launch_bounds__(TILE) void k_offsets(const int* __restrict__ deg, const int* __restrict__ tileBase,
                                                  int* __restrict__ offsets, int* __restrict__ cursor,
                                                  float* __restrict__ dinv, int n) {
    __shared__ int s[TILE];
    int t = threadIdx.x;
    int i = blockIdx.x * TILE + t;
    int dg = (i < n) ? deg[i] : 1;
    int v = dg - 1;
    s[t] = v;
    __syncthreads();
    for (int off = 1; off < TILE; off <<= 1) {
        int tmp = (t >= off) ? s[t - off] : 0;
        __syncthreads();
        s[t] += tmp;
        __syncthreads();
    }
    if (i < n) {
        int excl = s[t] - v + tileBase[blockIdx.x];
        offsets[i] = excl;
        cursor[i] = excl;
        dinv[i] = rsqrtf((float)dg);
    }
}

// ---------------------------------------------------------------- scan phase 3 (row: cursor only)
__global__ __launch_bounds__(TILE) void k_offsets_r(const int* __restrict__ cnt, const int* __restrict__ tileBase,
                                                    int* __restrict__ cursor, int n) {
    __shared__ int s[TILE];
    int t = threadIdx.x;
    int i = blockIdx.x * TILE + t;
    int v = (i < n) ? cnt[i] : 0;
    s[t] = v;
    __syncthreads();
    for (int off = 1; off < TILE; off <<= 1) {
        int tmp = (t >= off) ? s[t - off] : 0;
        __syncthreads();
        s[t] += tmp;
        __syncthreads();
    }
    if (i < n) cursor[i] = s[t] - v + tileBase[blockIdx.x];
}

// ---------------------------------------------------------------- fill A: bucket edges by SOURCE (perfect sort: same key per bucket)
__global__ __launch_bounds__(256) void k_fillA(const int* __restrict__ row, const int* __restrict__ col,
                                               int* __restrict__ rcur, int2* __restrict__ ep, int E) {
    int e = blockIdx.x * 256 + threadIdx.x;
    if (e < E) {
        int r = row[e];
        int p = atomicAdd(&rcur[r], 1);
        ep[p] = make_int2(r, col[e]);
    }
}

// ---------------------------------------------------------------- fill B: dest-CSR from source-sorted pairs
// Blocks dispatch ~in order -> each dest list is appended in ~ascending source order (locality heuristic only).
__global__ __launch_bounds__(256) void k_fillB(const int2* __restrict__ ep, int* __restrict__ cursor,
                                               int* __restrict__ csr, int E) {
    int e = blockIdx.x * 256 + threadIdx.x;
    if (e < E) {
        int2 rc = ep[e];
        int p = atomicAdd(&cursor[rc.y], 1);
        csr[p] = rc.x;
    }
}

// ---------------------------------------------------------------- pack W0 (natural k), W1 (P1-permuted k), biases (P1 positions)
__global__ __launch_bounds__(256) void k_packW(const float* __restrict__ w0, const float* __restrict__ w1,
                                               const float* __restrict__ b0, const float* __restrict__ b1,
                                               uint4* __restrict__ Wp0, uint4* __restrict__ Wp1,
                                               float* __restrict__ b0p, float* __restrict__ b1p) {
    int t = threadIdx.x;
    for (int e = t; e < 2048; e += 256) {
        int l = e & 63, U = (e >> 6) & 7, T = e >> 9;
        int nn = U * 16 + (l & 15);
        int kq = T * 32 + ((l >> 4) << 3);
        unsigned r[4], s[4];
#pragma unroll
        for (int jj = 0; jj < 4; ++jj) {
            int k0 = kq + 2 * jj, k1 = k0 + 1;
            unsigned a0 = f2bf(w0[k0 * 128 + nn]), a1 = f2bf(w0[k1 * 128 + nn]);
            r[jj] = a0 | (a1 << 16);
            int c0 = ((k0 & 7) << 4) | (k0 >> 3), c1 = ((k1 & 7) << 4) | (k1 >> 3);
            unsigned q0 = f2bf(w1[c0 * 128 + nn]), q1 = f2bf(w1[c1 * 128 + nn]);
            s[jj] = q0 | (q1 << 16);
        }
        Wp0[e] = make_uint4(r[0], r[1], r[2], r[3]);
        Wp1[e] = make_uint4(s[0], s[1], s[2], s[3]);
    }
    if (t < 128) {
        int c = ((t & 7) << 4) | (t >> 3);
        b0p[t] = b0[c];
        b1p[t] = b1[c];
    }
}

// ---------------------------------------------------------------- MFMA GEMM, fp32 row-major input (conv0)
__global__ __launch_bounds__(256) void k_gemm0(const float* __restrict__ x, const uint4* __restrict__ Wp,
                                               const float* __restrict__ dinv, unsigned* __restrict__ outb, int n) {
    int wave = threadIdx.x >> 6, l = threadIdx.x & 63;
    int mt = blockIdx.x * 4 + wave;
    int r0 = mt * 16;
    if (r0 >= n) return;                    // n % 16 == 0
    int rowA = r0 + (l & 15);
    int kq = (l >> 4) * 8;
    f32x4 acc[8];
#pragma unroll
    for (int U = 0; U < 8; ++U) acc[U] = (f32x4){0.f, 0.f, 0.f, 0.f};
    const float* xr = x + (size_t)rowA * 128 + kq;
#pragma unroll
    for (int T = 0; T < 4; ++T) {
        float4 a0 = *(const float4*)(xr + T * 32);
        float4 a1 = *(const float4*)(xr + T * 32 + 4);
        short8 af;
        af[0] = (short)f2bf(a0.x); af[1] = (short)f2bf(a0.y);
        af[2] = (short)f2bf(a0.z); af[3] = (short)f2bf(a0.w);
        af[4] = (short)f2bf(a1.x); af[5] = (short)f2bf(a1.y);
        af[6] = (short)f2bf(a1.z); af[7] = (short)f2bf(a1.w);
#pragma unroll
        for (int U = 0; U < 8; ++U) {
            short8 bf = *(const short8*)&Wp[(T * 8 + U) * 64 + l];
            acc[U] = __builtin_amdgcn_mfma_f32_16x16x32_bf16(af, bf, acc[U], 0, 0, 0);
        }
    }
    int rq = l >> 4, cl = l & 15;
#pragma unroll
    for (int q = 0; q < 4; ++q) {
        int rr = r0 + rq * 4 + q;
        float d = dinv[rr];
        uint4 w;
        w.x = (unsigned)f2bf(acc[0][q] * d) | ((unsigned)f2bf(acc[1][q] * d) << 16);
        w.y = (unsigned)f2bf(acc[2][q] * d) | ((unsigned)f2bf(acc[3][q] * d) << 16);
        w.z = (unsigned)f2bf(acc[4][q] * d) | ((unsigned)f2bf(acc[5][q] * d) << 16);
        w.w = (unsigned)f2bf(acc[6][q] * d) | ((unsigned)f2bf(acc[7][q] * d) << 16);
        *(uint4*)(outb + (size_t)rr * 64 + cl * 4) = w;
    }
}

// ---------------------------------------------------------------- MFMA GEMM, bf16 P1-ordered input (conv1)
__global__ __launch_bounds__(256) void k_gemm1(const unsigned* __restrict__ inb, const uint4* __restrict__ Wp,
                                               const float* __restrict__ dinv, unsigned* __restrict__ outb, int n) {
    int wave = threadIdx.x >> 6, l = threadIdx.x & 63;
    int mt = blockIdx.x * 4 + wave;
    int r0 = mt * 16;
    if (r0 >= n) return;
    int rowA = r0 + (l & 15);
    int kq4 = (l >> 4) * 4;                 // dword offset of 8-bf16 group
    f32x4 acc[8];
#pragma unroll
    for (int U = 0; U < 8; ++U) acc[U] = (f32x4){0.f, 0.f, 0.f, 0.f};
    const unsigned* ir = inb + (size_t)rowA * 64 + kq4;
#pragma unroll
    for (int T = 0; T < 4; ++T) {
        short8 af = *(const short8*)(ir + T * 16);
#pragma unroll
        for (int U = 0; U < 8; ++U) {
            short8 bf = *(const short8*)&Wp[(T * 8 + U) * 64 + l];
            acc[U] = __builtin_amdgcn_mfma_f32_16x16x32_bf16(af, bf, acc[U], 0, 0, 0);
        }
    }
    int rq = l >> 4, cl = l & 15;
#pragma unroll
    for (int q = 0; q < 4; ++q) {
        int rr = r0 + rq * 4 + q;
        float d = dinv[rr];
        uint4 w;
        w.x = (unsigned)f2bf(acc[0][q] * d) | ((unsigned)f2bf(acc[1][q] * d) << 16);
        w.y = (unsigned)f2bf(acc[2][q] * d) | ((unsigned)f2bf(acc[3][q] * d) << 16);
        w.z = (unsigned)f2bf(acc[4][q] * d) | ((unsigned)f2bf(acc[5][q] * d) << 16);
        w.w = (unsigned)f2bf(acc[6][q] * d) | ((unsigned)f2bf(acc[7][q] * d) << 16);
        *(uint4*)(outb + (size_t)rr * 64 + cl * 4) = w;
    }
}

// ---------------------------------------------------------------- dual-stream gather-sum core
__device__ inline void gather2(const unsigned* __restrict__ hp, const int* __restrict__ src,
                               int l, int beg, int end, float& AX, float& AY) {
    int len = end - beg;
    int h = len >> 1;
    int e0 = beg, end0 = beg + h;
    int e1 = end0, end1 = end;
    float ax0 = 0.f, ay0 = 0.f, ax1 = 0.f, ay1 = 0.f;
    while (e0 + 4 <= end0 && e1 + 4 <= end1) {
        int a0 = src[e0], a1 = src[e0 + 1], a2 = src[e0 + 2], a3 = src[e0 + 3];
        int b0 = src[e1], b1 = src[e1 + 1], b2 = src[e1 + 2], b3 = src[e1 + 3];
        unsigned u0 = hp[(size_t)a0 * 64 + l];
        unsigned u1 = hp[(size_t)a1 * 64 + l];
        unsigned u2 = hp[(size_t)a2 * 64 + l];
        unsigned u3 = hp[(size_t)a3 * 64 + l];
        unsigned u4 = hp[(size_t)b0 * 64 + l];
        unsigned u5 = hp[(size_t)b1 * 64 + l];
        unsigned u6 = hp[(size_t)b2 * 64 + l];
        unsigned u7 = hp[(size_t)b3 * 64 + l];
        ax0 += bflo(u0) + bflo(u1) + bflo(u2) + bflo(u3);
        ay0 += bfhi(u0) + bfhi(u1) + bfhi(u2) + bfhi(u3);
        ax1 += bflo(u4) + bflo(u5) + bflo(u6) + bflo(u7);
        ay1 += bfhi(u4) + bfhi(u5) + bfhi(u6) + bfhi(u7);
        e0 += 4; e1 += 4;
    }
    for (; e0 < end0; ++e0) {
        unsigned v = hp[(size_t)src[e0] * 64 + l];
        ax0 += bflo(v); ay0 += bfhi(v);
    }
    for (; e1 < end1; ++e1) {
        unsigned v = hp[(size_t)src[e1] * 64 + l];
        ax1 += bflo(v); ay1 += bfhi(v);
    }
    AX += ax0 + ax1;
    AY += ay0 + ay1;
}

// ---------------------------------------------------------------- agg conv0
__global__ __launch_bounds__(256) void k_agg0(const unsigned* __restrict__ hp, const int* __restrict__ offs,
                                              const int* __restrict__ src, const float* __restrict__ dinv,
                                              const float* __restrict__ bp, unsigned* __restrict__ outb, int n) {
    int wid = (blockIdx.x * 256 + threadIdx.x) >> 6;
    int l = threadIdx.x & 63;
    if (wid >= n) return;
    unsigned u = hp[(size_t)wid * 64 + l];
    float ax = bflo(u), ay = bfhi(u);
    gather2(hp, src, l, offs[wid], offs[wid + 1], ax, ay);
    float d = dinv[wid];
    float2 b = ((const float2*)bp)[l];
    float ox = fmaxf(fmaf(d, ax, b.x), 0.f);
    float oy = fmaxf(fmaf(d, ay, b.y), 0.f);
    outb[(size_t)wid * 64 + l] = (unsigned)f2bf(ox) | ((unsigned)f2bf(oy) << 16);
}

// ---------------------------------------------------------------- agg conv1 + fused segment-max pool
__global__ __launch_bounds__(256) void k_agg1(const unsigned* __restrict__ hp, const int* __restrict__ offs,
                                              const int* __restrict__ src, const float* __restrict__ dinv,
                                              const float* __restrict__ bp, const int* __restrict__ batch,
                                              int* __restrict__ pool, int n) {
    __shared__ float2 sv[4][64];
    __shared__ int sg[4];
    int w = threadIdx.x >> 6, l = threadIdx.x & 63;
    int wid = blockIdx.x * 4 + w;
    float ox = 0.f, oy = 0.f;
    if (wid < n) {
        unsigned u = hp[(size_t)wid * 64 + l];
        float ax = bflo(u), ay = bfhi(u);
        gather2(hp, src, l, offs[wid], offs[wid + 1], ax, ay);
        float d = dinv[wid];
        float2 b = ((const float2*)bp)[l];
        ox = fmaxf(fmaf(d, ax, b.x), 0.f);
        oy = fmaxf(fmaf(d, ay, b.y), 0.f);
        if (l == 0) sg[w] = batch[wid];
    } else if (l == 0) {
        sg[w] = -1;
    }
    sv[w][l] = make_float2(ox, oy);
    __syncthreads();
    if (threadIdx.x < 64) {
        int t = threadIdx.x;
        int c0 = 32 * (t & 3) + (t >> 2);           // true col of position 2t; pair col = c0+16
        int cur = sg[0];
        float2 m = sv[0][t];
        for (int ww = 1; ww < 4; ++ww) {
            int g = sg[ww];
            if (g < 0) break;                        // batch sorted; invalid only at tail
            float2 v = sv[ww][t];
            if (g == cur) { m.x = fmaxf(m.x, v.x); m.y = fmaxf(m.y, v.y); }
            else {
                atomicMax(&pool[cur * 128 + c0], __float_as_int(m.x));
                atomicMax(&pool[cur * 128 + c0 + 16], __float_as_int(m.y));
                cur = g; m = v;
            }
        }
        atomicMax(&pool[cur * 128 + c0], __float_as_int(m.x));
        atomicMax(&pool[cur * 128 + c0 + 16], __float_as_int(m.y));
    }
}

// ---------------------------------------------------------------- pool init
__global__ __launch_bounds__(128) void k_pool_init(int* __restrict__ pool) {
    pool[blockIdx.x * 128 + threadIdx.x] = 0;
}

// ---------------------------------------------------------------- final MLP + log_softmax, 1 block/graph
__global__ __launch_bounds__(128) void k_mlp(const float* __restrict__ pool, const float* __restrict__ W0,
                                             const float* __restrict__ b0, const float* __restrict__ W1,
                                             const float* __restrict__ b1, float* __restrict__ out) {
    __shared__ float rowv[128];
    __shared__ float h2[128];
    __shared__ float h3[10];
    int g = blockIdx.x, t = threadIdx.x;
    rowv[t] = pool[g * 128 + t];
    __syncthreads();
    float acc = b0[t];
    for (int k = 0; k < 128; ++k) acc = fmaf(rowv[k], W0[k * 128 + t], acc);
    h2[t] = fmaxf(acc, 0.f);
    __syncthreads();
    if (t < 10) {
        float a = b1[t];
        for (int k = 0; k < 128; ++k) a = fmaf(h2[k], W1[k * 10 + t], a);
        h3[t] = fmaxf(a, 0.f);
    }
    __syncthreads();
    if (t == 0) {
        float mx = h3[0];
        for (int j = 1; j < 10; ++j) mx = fmaxf(mx, h3[j]);
        float s = 0.f;
        for (int j = 0; j < 10; ++j) s += expf(h3[j] - mx);
        float lse = logf(s) + mx;
        for (int j = 0; j < 10; ++j) out[g * 10 + j] = h3[j] - lse;
    }
}

// ----------------------------------------------------------------
extern "C" void kernel_launch(void* const* d_in, const int* in_sizes, int n_in,
                              void* d_out, int out_size, void* d_ws, size_t ws_size,
                              hipStream_t stream) {
    const float* x   = (const float*)d_in[0];
    const int* eidx  = (const int*)d_in[1];
    const int* batch = (const int*)d_in[2];
    const float* w0  = (const float*)d_in[3];
    const float* b0  = (const float*)d_in[4];
    const float* w1  = (const float*)d_in[5];
    const float* b1  = (const float*)d_in[6];
    const float* lw0 = (const float*)d_in[7];
    const float* lb0 = (const float*)d_in[8];
    const float* lw1 = (const float*)d_in[9];
    const float* lb1 = (const float*)d_in[10];
    float* out = (float*)d_out;

    int n = in_sizes[2];
    int E = in_sizes[1] / 2;
    const int* row = eidx;        // sources
    const int* col = eidx + E;    // destinations
    int nTiles = (n + TILE - 1) / TILE;

    char* ws = (char*)d_ws;
    size_t o = 0;
    auto take = [&](size_t bytes) { void* p = ws + o; o += (bytes + 255) & ~(size_t)255; return p; };
    int*      deg      = (int*)     take((size_t)n * 4);
    int*      rdeg     = (int*)     take((size_t)n * 4);
    int*      offsets  = (int*)     take((size_t)(n + 1) * 4);
    int*      cursor   = (int*)     take((size_t)n * 4);
    int*      rcur     = (int*)     take((size_t)n * 4);
    int*      csr      = (int*)     take((size_t)E * 4);
    int2*     epairs   = (int2*)    take((size_t)E * 8);
    float*    dinv     = (float*)   take((size_t)n * 4);
    int*      tileSum  = (int*)     take((size_t)nTiles * 4);
    int*      tileBase = (int*)     take((size_t)nTiles * 4);
    int*      rtotal   = (int*)     take(4);
    uint4*    Wp0      = (uint4*)   take(2048 * 16);
    uint4*    Wp1      = (uint4*)   take(2048 * 16);
    float*    b0p      = (float*)   take(128 * 4);
    float*    b1p      = (float*)   take(128 * 4);
    unsigned* h0b      = (unsigned*)take((size_t)n * 64 * 4);   // bf16 P1 rows
    unsigned* h1i      = (unsigned*)take((size_t)n * 64 * 4);
    unsigned* h1b      = (unsigned*)take((size_t)n * 64 * 4);
    int*      pool     = (int*)     take(64 * 128 * 4);

    k_deg_init<<<(n + 255) / 256, 256, 0, stream>>>(deg, rdeg, n);
    k_count<<<(E + 255) / 256, 256, 0, stream>>>(col, deg, E);
    k_count_row<<<(E + 255) / 256, 256, 0, stream>>>(row, rdeg, E);
    // dest-CSR offsets
    k_tilesum<<<nTiles, TILE, 0, stream>>>(deg, tileSum, n);
    k_tilescan<<<1, TILE, 0, stream>>>(tileSum, tileBase, &offsets[n], nTiles);
    k_offsets<<<nTiles, TILE, 0, stream>>>(deg, tileBase, offsets, cursor, dinv, n);
    // source-bucket cursors
    k_tilesum_r<<<nTiles, TILE, 0, stream>>>(rdeg, tileSum, n);
    k_tilescan<<<1, TILE, 0, stream>>>(tileSum, tileBase, rtotal, nTiles);
    k_offsets_r<<<nTiles, TILE, 0, stream>>>(rdeg, tileBase, rcur, n);
    // sort edges by source, then fill dest-CSR in ~source order
    k_fillA<<<(E + 255) / 256, 256, 0, stream>>>(row, col, rcur, epairs, E);
    k_fillB<<<(E + 255) / 256, 256, 0, stream>>>(epairs, cursor, csr, E);

    k_packW<<<1, 256, 0, stream>>>(w0, w1, b0, b1, Wp0, Wp1, b0p, b1p);
    k_pool_init<<<64, 128, 0, stream>>>(pool);

    int mtBlocks = ((n + 15) / 16 + 3) / 4;     // 4 waves/block, 1 mtile/wave

    // conv0
    k_gemm0<<<mtBlocks, 256, 0, stream>>>(x, Wp0, dinv, h0b, n);
    k_agg0<<<(n + 3) / 4, 256, 0, stream>>>(h0b, offsets, csr, dinv, b0p, h1i, n);
    // conv1 (+ fused pool)
    k_gemm1<<<mtBlocks, 256, 0, stream>>>(h1i, Wp1, dinv, h1b, n);
    k_agg1<<<(n + 3) / 4, 256, 0, stream>>>(h1b, offsets, csr, dinv, b1p, batch, pool, n);

    k_mlp<<<64, 128, 0, stream>>>((const float*)pool, lw0, lb0, lw1, lb1, out);
}

// Round 8
// 250.055 us; speedup vs baseline: 1.6050x; 1.6050x over previous
//
#include <hip/hip_runtime.h>

#define D 128
#define P2CAP 6144

typedef __attribute__((ext_vector_type(8))) short short8;
typedef __attribute__((ext_vector_type(4))) float f32x4;

__device__ inline unsigned short f2bf(float f) {
    unsigned u = __float_as_uint(f);
    return (unsigned short)((u + 0x7FFFu + ((u >> 16) & 1u)) >> 16);
}
__device__ inline float bflo(unsigned u) { return __uint_as_float(u << 16); }
__device__ inline float bfhi(unsigned u) { return __uint_as_float(u & 0xFFFF0000u); }

// ---------------------------------------------------------------- pass1 hist: 256-wide coarse bins (dst>>8)
__global__ __launch_bounds__(256) void k_p1hist(const int* __restrict__ col, int* __restrict__ binCnt, int E) {
    __shared__ int h[256];
    int t = threadIdx.x;
    h[t] = 0;
    __syncthreads();
    int base = blockIdx.x * 4096;
#pragma unroll
    for (int k = 0; k < 16; ++k) {
        int e = base + k * 256 + t;
        if (e < E) atomicAdd(&h[col[e] >> 8], 1);
    }
    __syncthreads();
    if (h[t]) atomicAdd(&binCnt[t], h[t]);
}

// ---------------------------------------------------------------- bin scan (1 block): binBase/binCur, offsets[n]=E
__global__ __launch_bounds__(256) void k_binscan(const int* __restrict__ binCnt, int* __restrict__ binBase,
                                                 int* __restrict__ binCur, int* __restrict__ offsets,
                                                 int nbins, int n, int E) {
    __shared__ int s[256];
    int t = threadIdx.x;
    int v = (t < nbins) ? binCnt[t] : 0;
    s[t] = v;
    __syncthreads();
    for (int off = 1; off < 256; off <<= 1) {
        int tmp = (t >= off) ? s[t - off] : 0;
        __syncthreads();
        s[t] += tmp;
        __syncthreads();
    }
    int excl = s[t] - v;
    if (t < nbins) { binBase[t] = excl; binCur[t] = excl; }
    if (t == 0) { binBase[nbins] = E; offsets[n] = E; }
}

// ---------------------------------------------------------------- pass1 scatter: LDS-group by bin, write contiguous runs
__global__ __launch_bounds__(256) void k_p1scatter(const int* __restrict__ row, const int* __restrict__ col,
                                                   int* __restrict__ binCur, unsigned* __restrict__ ebuf, int E) {
    __shared__ int h[256], s[256], lscan[256], delta[256], lcur[256];
    __shared__ unsigned stage[4096];
    int t = threadIdx.x;
    h[t] = 0;
    __syncthreads();
    int base = blockIdx.x * 4096;
    int cnt = min(4096, E - base);
#pragma unroll
    for (int k = 0; k < 16; ++k) {
        int e = base + k * 256 + t;
        if (e < E) atomicAdd(&h[col[e] >> 8], 1);
    }
    __syncthreads();
    int v = h[t];
    s[t] = v;
    __syncthreads();
    for (int off = 1; off < 256; off <<= 1) {
        int tmp = (t >= off) ? s[t - off] : 0;
        __syncthreads();
        s[t] += tmp;
        __syncthreads();
    }
    int excl = s[t] - v;
    lscan[t] = excl;
    lcur[t] = excl;
    delta[t] = (v > 0) ? (atomicAdd(&binCur[t], v) - excl) : 0;
    __syncthreads();
#pragma unroll
    for (int k = 0; k < 16; ++k) {
        int e = base + k * 256 + t;
        if (e < E) {
            int d = col[e];
            int slot = atomicAdd(&lcur[d >> 8], 1);
            stage[slot] = ((unsigned)d << 16) | (unsigned)row[e];   // n < 2^16: both fit
        }
    }
    __syncthreads();
#pragma unroll
    for (int k = 0; k < 16; ++k) {
        int slot = k * 256 + t;
        if (slot < cnt) {
            unsigned vv = stage[slot];
            int b = vv >> 24;                       // = dst >> 8
            ebuf[delta[b] + slot] = vv;
        }
    }
}

// ---------------------------------------------------------------- pass2: per-bin exact counting sort -> csr/offsets/dinv
__global__ __launch_bounds__(256) void k_p2sort(const unsigned* __restrict__ ebuf, const int* __restrict__ binBase,
                                                int* __restrict__ csr, int* __restrict__ offsets,
                                                float* __restrict__ dinv, int n) {
    __shared__ unsigned stage[P2CAP];
    __shared__ unsigned stage2[P2CAP];
    __shared__ int h[256], s[256], cur[256];
    int b = blockIdx.x, t = threadIdx.x;
    int beg = binBase[b], end = binBase[b + 1];
    int cnt = end - beg;                            // ~4080 avg; P2CAP=6144 is ~30 sigma margin
    h[t] = 0;
    __syncthreads();
    for (int i = t; i < cnt; i += 256) {
        unsigned v = ebuf[beg + i];
        stage[i] = v;
        atomicAdd(&h[(v >> 16) & 0xFF], 1);
    }
    __syncthreads();
    int v = h[t];
    s[t] = v;
    __syncthreads();
    for (int off = 1; off < 256; off <<= 1) {
        int tmp = (t >= off) ? s[t - off] : 0;
        __syncthreads();
        s[t] += tmp;
        __syncthreads();
    }
    int excl = s[t] - v;
    cur[t] = excl;
    int d = b * 256 + t;
    if (d < n) {
        offsets[d] = beg + excl;
        dinv[d] = rsqrtf((float)(v + 1));           // +1 self-loop
    }
    __syncthreads();
    for (int i = t; i < cnt; i += 256) {
        unsigned vv = stage[i];
        int slot = atomicAdd(&cur[(vv >> 16) & 0xFF], 1);
        stage2[slot] = vv & 0xFFFFu;
    }
    __syncthreads();
    for (int i = t; i < cnt; i += 256) csr[beg + i] = (int)stage2[i];
}

// ---------------------------------------------------------------- pack W0 (natural k), W1 (P1-permuted k), biases (P1 positions)
__global__ __launch_bounds__(256) void k_packW(const float* __restrict__ w0, const float* __restrict__ w1,
                                               const float* __restrict__ b0, const float* __restrict__ b1,
                                               uint4* __restrict__ Wp0, uint4* __restrict__ Wp1,
                                               float* __restrict__ b0p, float* __restrict__ b1p) {
    int t = threadIdx.x;
    for (int e = t; e < 2048; e += 256) {
        int l = e & 63, U = (e >> 6) & 7, T = e >> 9;
        int nn = U * 16 + (l & 15);
        int kq = T * 32 + ((l >> 4) << 3);
        unsigned r[4], s[4];
#pragma unroll
        for (int jj = 0; jj < 4; ++jj) {
            int k0 = kq + 2 * jj, k1 = k0 + 1;
            unsigned a0 = f2bf(w0[k0 * 128 + nn]), a1 = f2bf(w0[k1 * 128 + nn]);
            r[jj] = a0 | (a1 << 16);
            int c0 = ((k0 & 7) << 4) | (k0 >> 3), c1 = ((k1 & 7) << 4) | (k1 >> 3);
            unsigned q0 = f2bf(w1[c0 * 128 + nn]), q1 = f2bf(w1[c1 * 128 + nn]);
            s[jj] = q0 | (q1 << 16);
        }
        Wp0[e] = make_uint4(r[0], r[1], r[2], r[3]);
        Wp1[e] = make_uint4(s[0], s[1], s[2], s[3]);
    }
    if (t < 128) {
        int c = ((t & 7) << 4) | (t >> 3);
        b0p[t] = b0[c];
        b1p[t] = b1[c];
    }
}

// ---------------------------------------------------------------- MFMA GEMM, fp32 row-major input (conv0)
__global__ __launch_bounds__(256) void k_gemm0(const float* __restrict__ x, const uint4* __restrict__ Wp,
                                               const float* __restrict__ dinv, unsigned* __restrict__ outb, int n) {
    int wave = threadIdx.x >> 6, l = threadIdx.x & 63;
    int mt = blockIdx.x * 4 + wave;
    int r0 = mt * 16;
    if (r0 >= n) return;                    // n % 16 == 0
    int rowA = r0 + (l & 15);
    int kq = (l >> 4) * 8;
    f32x4 acc[8];
#pragma unroll
    for (int U = 0; U < 8; ++U) acc[U] = (f32x4){0.f, 0.f, 0.f, 0.f};
    const float* xr = x + (size_t)rowA * 128 + kq;
#pragma unroll
    for (int T = 0; T < 4; ++T) {
        float4 a0 = *(const float4*)(xr + T * 32);
        float4 a1 = *(const float4*)(xr + T * 32 + 4);
        short8 af;
        af[0] = (short)f2bf(a0.x); af[1] = (short)f2bf(a0.y);
        af[2] = (short)f2bf(a0.z); af[3] = (short)f2bf(a0.w);
        af[4] = (short)f2bf(a1.x); af[5] = (short)f2bf(a1.y);
        af[6] = (short)f2bf(a1.z); af[7] = (short)f2bf(a1.w);
#pragma unroll
        for (int U = 0; U < 8; ++U) {
            short8 bf = *(const short8*)&Wp[(T * 8 + U) * 64 + l];
            acc[U] = __builtin_amdgcn_mfma_f32_16x16x32_bf16(af, bf, acc[U], 0, 0, 0);
        }
    }
    int rq = l >> 4, cl = l & 15;
#pragma unroll
    for (int q = 0; q < 4; ++q) {
        int rr = r0 + rq * 4 + q;
        float d = dinv[rr];
        uint4 w;
        w.x = (unsigned)f2bf(acc[0][q] * d) | ((unsigned)f2bf(acc[1][q] * d) << 16);
        w.y = (unsigned)f2bf(acc[2][q] * d) | ((unsigned)f2bf(acc[3][q] * d) << 16);
        w.z = (unsigned)f2bf(acc[4][q] * d) | ((unsigned)f2bf(acc[5][q] * d) << 16);
        w.w = (unsigned)f2bf(acc[6][q] * d) | ((unsigned)f2bf(acc[7][q] * d) << 16);
        *(uint4*)(outb + (size_t)rr * 64 + cl * 4) = w;
    }
}

// ---------------------------------------------------------------- MFMA GEMM, bf16 P1-ordered input (conv1)
__global__ __launch_bounds__(256) void k_gemm1(const unsigned* __restrict__ inb, const uint4* __restrict__ Wp,
                                               const float* __restrict__ dinv, unsigned* __restrict__ outb, int n) {
    int wave = threadIdx.x >> 6, l = threadIdx.x & 63;
    int mt = blockIdx.x * 4 + wave;
    int r0 = mt * 16;
    if (r0 >= n) return;
    int rowA = r0 + (l & 15);
    int kq4 = (l >> 4) * 4;                 // dword offset of 8-bf16 group
    f32x4 acc[8];
#pragma unroll
    for (int U = 0; U < 8; ++U) acc[U] = (f32x4){0.f, 0.f, 0.f, 0.f};
    const unsigned* ir = inb + (size_t)rowA * 64 + kq4;
#pragma unroll
    for (int T = 0; T < 4; ++T) {
        short8 af = *(const short8*)(ir + T * 16);
#pragma unroll
        for (int U = 0; U < 8; ++U) {
            short8 bf = *(const short8*)&Wp[(T * 8 + U) * 64 + l];
            acc[U] = __builtin_amdgcn_mfma_f32_16x16x32_bf16(af, bf, acc[U], 0, 0, 0);
        }
    }
    int rq = l >> 4, cl = l & 15;
#pragma unroll
    for (int q = 0; q < 4; ++q) {
        int rr = r0 + rq * 4 + q;
        float d = dinv[rr];
        uint4 w;
        w.x = (unsigned)f2bf(acc[0][q] * d) | ((unsigned)f2bf(acc[1][q] * d) << 16);
        w.y = (unsigned)f2bf(acc[2][q] * d) | ((unsigned)f2bf(acc[3][q] * d) << 16);
        w.z = (unsigned)f2bf(acc[4][q] * d) | ((unsigned)f2bf(acc[5][q] * d) << 16);
        w.w = (unsigned)f2bf(acc[6][q] * d) | ((unsigned)f2bf(acc[7][q] * d) << 16);
        *(uint4*)(outb + (size_t)rr * 64 + cl * 4) = w;
    }
}

// ---------------------------------------------------------------- dual-stream gather-sum core
__device__ inline void gather2(const unsigned* __restrict__ hp, const int* __restrict__ src,
                               int l, int beg, int end, float& AX, float& AY) {
    int len = end - beg;
    int h = len >> 1;
    int e0 = beg, end0 = beg + h;
    int e1 = end0, end1 = end;
    float ax0 = 0.f, ay0 = 0.f, ax1 = 0.f, ay1 = 0.f;
    while (e0 + 4 <= end0 && e1 + 4 <= end1) {
        int a0 = src[e0], a1 = src[e0 + 1], a2 = src[e0 + 2], a3 = src[e0 + 3];
        int b0 = src[e1], b1 = src[e1 + 1], b2 = src[e1 + 2], b3 = src[e1 + 3];
        unsigned u0 = hp[(size_t)a0 * 64 + l];
        unsigned u1 = hp[(size_t)a1 * 64 + l];
        unsigned u2 = hp[(size_t)a2 * 64 + l];
        unsigned u3 = hp[(size_t)a3 * 64 + l];
        unsigned u4 = hp[(size_t)b0 * 64 + l];
        unsigned u5 = hp[(size_t)b1 * 64 + l];
        unsigned u6 = hp[(size_t)b2 * 64 + l];
        unsigned u7 = hp[(size_t)b3 * 64 + l];
        ax0 += bflo(u0) + bflo(u1) + bflo(u2) + bflo(u3);
        ay0 += bfhi(u0) + bfhi(u1) + bfhi(u2) + bfhi(u3);
        ax1 += bflo(u4) + bflo(u5) + bflo(u6) + bflo(u7);
        ay1 += bfhi(u4) + bfhi(u5) + bfhi(u6) + bfhi(u7);
        e0 += 4; e1 += 4;
    }
    for (; e0 < end0; ++e0) {
        unsigned v = hp[(size_t)src[e0] * 64 + l];
        ax0 += bflo(v); ay0 += bfhi(v);
    }
    for (; e1 < end1; ++e1) {
        unsigned v = hp[(size_t)src[e1] * 64 + l];
        ax1 += bflo(v); ay1 += bfhi(v);
    }
    AX += ax0 + ax1;
    AY += ay0 + ay1;
}

// ---------------------------------------------------------------- agg conv0
__global__ __launch_bounds__(256) void k_agg0(const unsigned* __restrict__ hp, const int* __restrict__ offs,
                                              const int* __restrict__ src, const float* __restrict__ dinv,
                                              const float* __restrict__ bp, unsigned* __restrict__ outb, int n) {
    int wid = (blockIdx.x * 256 + threadIdx.x) >> 6;
    int l = threadIdx.x & 63;
    if (wid >= n) return;
    unsigned u = hp[(size_t)wid * 64 + l];
    float ax = bflo(u), ay = bfhi(u);
    gather2(hp, src, l, offs[wid], offs[wid + 1], ax, ay);
    float d = dinv[wid];
    float2 b = ((const float2*)bp)[l];
    float ox = fmaxf(fmaf(d, ax, b.x), 0.f);
    float oy = fmaxf(fmaf(d, ay, b.y), 0.f);
    outb[(size_t)wid * 64 + l] = (unsigned)f2bf(ox) | ((unsigned)f2bf(oy) << 16);
}

// ---------------------------------------------------------------- agg conv1 + fused segment-max pool
__global__ __launch_bounds__(256) void k_agg1(const unsigned* __restrict__ hp, const int* __restrict__ offs,
                                              const int* __restrict__ src, const float* __restrict__ dinv,
                                              const float* __restrict__ bp, const int* __restrict__ batch,
                                              int* __restrict__ pool, int n) {
    __shared__ float2 sv[4][64];
    __shared__ int sg[4];
    int w = threadIdx.x >> 6, l = threadIdx.x & 63;
    int wid = blockIdx.x * 4 + w;
    float ox = 0.f, oy = 0.f;
    if (wid < n) {
        unsigned u = hp[(size_t)wid * 64 + l];
        float ax = bflo(u), ay = bfhi(u);
        gather2(hp, src, l, offs[wid], offs[wid + 1], ax, ay);
        float d = dinv[wid];
        float2 b = ((const float2*)bp)[l];
        ox = fmaxf(fmaf(d, ax, b.x), 0.f);
        oy = fmaxf(fmaf(d, ay, b.y), 0.f);
        if (l == 0) sg[w] = batch[wid];
    } else if (l == 0) {
        sg[w] = -1;
    }
    sv[w][l] = make_float2(ox, oy);
    __syncthreads();
    if (threadIdx.x < 64) {
        int t = threadIdx.x;
        int c0 = 32 * (t & 3) + (t >> 2);           // true col of position 2t; pair col = c0+16
        int cur = sg[0];
        float2 m = sv[0][t];
        for (int ww = 1; ww < 4; ++ww) {
            int g = sg[ww];
            if (g < 0) break;                        // batch sorted; invalid only at tail
            float2 v = sv[ww][t];
            if (g == cur) { m.x = fmaxf(m.x, v.x); m.y = fmaxf(m.y, v.y); }
            else {
                atomicMax(&pool[cur * 128 + c0], __float_as_int(m.x));
                atomicMax(&pool[cur * 128 + c0 + 16], __float_as_int(m.y));
                cur = g; m = v;
            }
        }
        atomicMax(&pool[cur * 128 + c0], __float_as_int(m.x));
        atomicMax(&pool[cur * 128 + c0 + 16], __float_as_int(m.y));
    }
}

// ---------------------------------------------------------------- final MLP + log_softmax, 1 block/graph
__global__ __launch_bounds__(128) void k_mlp(const float* __restrict__ pool, const float* __restrict__ W0,
                                             const float* __restrict__ b0, const float* __restrict__ W1,
                                             const float* __restrict__ b1, float* __restrict__ out) {
    __shared__ float rowv[128];
    __shared__ float h2[128];
    __shared__ float h3[10];
    int g = blockIdx.x, t = threadIdx.x;
    rowv[t] = pool[g * 128 + t];
    __syncthreads();
    float acc = b0[t];
    for (int k = 0; k < 128; ++k) acc = fmaf(rowv[k], W0[k * 128 + t], acc);
    h2[t] = fmaxf(acc, 0.f);
    __syncthreads();
    if (t < 10) {
        float a = b1[t];
        for (int k = 0; k < 128; ++k) a = fmaf(h2[k], W1[k * 10 + t], a);
        h3[t] = fmaxf(a, 0.f);
    }
    __syncthreads();
    if (t == 0) {
        float mx = h3[0];
        for (int j = 1; j < 10; ++j) mx = fmaxf(mx, h3[j]);
        float s = 0.f;
        for (int j = 0; j < 10; ++j) s += expf(h3[j] - mx);
        float lse = logf(s) + mx;
        for (int j = 0; j < 10; ++j) out[g * 10 + j] = h3[j] - lse;
    }
}

// ----------------------------------------------------------------
extern "C" void kernel_launch(void* const* d_in, const int* in_sizes, int n_in,
                              void* d_out, int out_size, void* d_ws, size_t ws_size,
                              hipStream_t stream) {
    const float* x   = (const float*)d_in[0];
    const int* eidx  = (const int*)d_in[1];
    const int* batch = (const int*)d_in[2];
    const float* w0  = (const float*)d_in[3];
    const float* b0  = (const float*)d_in[4];
    const float* w1  = (const float*)d_in[5];
    const float* b1  = (const float*)d_in[6];
    const float* lw0 = (const float*)d_in[7];
    const float* lb0 = (const float*)d_in[8];
    const float* lw1 = (const float*)d_in[9];
    const float* lb1 = (const float*)d_in[10];
    float* out = (float*)d_out;

    int n = in_sizes[2];
    int E = in_sizes[1] / 2;
    const int* row = eidx;        // sources
    const int* col = eidx + E;    // destinations
    int nbins = (n + 255) >> 8;   // 196 coarse bins (n < 2^16 required for packing)
    int nb1 = (E + 4095) / 4096;  // pass-1 blocks

    char* ws = (char*)d_ws;
    size_t o = 0;
    auto take = [&](size_t bytes) { void* p = ws + o; o += (bytes + 255) & ~(size_t)255; return p; };
    int*      binCnt   = (int*)     take(256 * 4);
    int*      binBase  = (int*)     take(260 * 4);
    int*      binCur   = (int*)     take(256 * 4);
    int*      offsets  = (int*)     take((size_t)(n + 1) * 4);
    float*    dinv     = (float*)   take((size_t)n * 4);
    int*      csr      = (int*)     take((size_t)E * 4);
    unsigned* ebuf     = (unsigned*)take((size_t)E * 4);
    uint4*    Wp0      = (uint4*)   take(2048 * 16);
    uint4*    Wp1      = (uint4*)   take(2048 * 16);
    float*    b0p      = (float*)   take(128 * 4);
    float*    b1p      = (float*)   take(128 * 4);
    unsigned* h0b      = (unsigned*)take((size_t)n * 64 * 4);   // bf16 P1 rows
    unsigned* h1i      = (unsigned*)take((size_t)n * 64 * 4);
    unsigned* h1b      = (unsigned*)take((size_t)n * 64 * 4);
    int*      pool     = (int*)     take(64 * 128 * 4);

    hipMemsetAsync(binCnt, 0, 256 * 4, stream);
    hipMemsetAsync(pool, 0, 64 * 128 * 4, stream);

    // CSR build: 2-pass LDS-staged bucket sort (no fine-grained global scatter)
    k_p1hist<<<nb1, 256, 0, stream>>>(col, binCnt, E);
    k_binscan<<<1, 256, 0, stream>>>(binCnt, binBase, binCur, offsets, nbins, n, E);
    k_p1scatter<<<nb1, 256, 0, stream>>>(row, col, binCur, ebuf, E);
    k_p2sort<<<nbins, 256, 0, stream>>>(ebuf, binBase, csr, offsets, dinv, n);

    k_packW<<<1, 256, 0, stream>>>(w0, w1, b0, b1, Wp0, Wp1, b0p, b1p);

    int mtBlocks = ((n + 15) / 16 + 3) / 4;     // 4 waves/block, 1 mtile/wave

    // conv0
    k_gemm0<<<mtBlocks, 256, 0, stream>>>(x, Wp0, dinv, h0b, n);
    k_agg0<<<(n + 3) / 4, 256, 0, stream>>>(h0b, offsets, csr, dinv, b0p, h1i, n);
    // conv1 (+ fused pool)
    k_gemm1<<<mtBlocks, 256, 0, stream>>>(h1i, Wp1, dinv, h1b, n);
    k_agg1<<<(n + 3) / 4, 256, 0, stream>>>(h1b, offsets, csr, dinv, b1p, batch, pool, n);

    k_mlp<<<64, 128, 0, stream>>>((const float*)pool, lw0, lb0, lw1, lb1, out);
}

// Round 9
// 237.962 us; speedup vs baseline: 1.6865x; 1.0508x over previous
//
#include <hip/hip_runtime.h>

#define D 128
#define P2CAP 6144

typedef __attribute__((ext_vector_type(8))) short short8;
typedef __attribute__((ext_vector_type(4))) float f32x4;

__device__ inline unsigned short f2bf(float f) {
    unsigned u = __float_as_uint(f);
    return (unsigned short)((u + 0x7FFFu + ((u >> 16) & 1u)) >> 16);
}
__device__ inline float bflo(unsigned u) { return __uint_as_float(u << 16); }
__device__ inline float bfhi(unsigned u) { return __uint_as_float(u & 0xFFFF0000u); }

// ---------------------------------------------------------------- pass1 hist: 256-wide coarse bins (dst>>8)
__global__ __launch_bounds__(256) void k_p1hist(const int* __restrict__ col, int* __restrict__ binCnt, int E) {
    __shared__ int h[256];
    int t = threadIdx.x;
    h[t] = 0;
    __syncthreads();
    int base = blockIdx.x * 4096;
#pragma unroll
    for (int k = 0; k < 16; ++k) {
        int e = base + k * 256 + t;
        if (e < E) atomicAdd(&h[col[e] >> 8], 1);
    }
    __syncthreads();
    if (h[t]) atomicAdd(&binCnt[t], h[t]);
}

// ---------------------------------------------------------------- bin scan (1 block)
__global__ __launch_bounds__(256) void k_binscan(const int* __restrict__ binCnt, int* __restrict__ binBase,
                                                 int* __restrict__ binCur, int* __restrict__ offsets,
                                                 int nbins, int n, int E) {
    __shared__ int s[256];
    int t = threadIdx.x;
    int v = (t < nbins) ? binCnt[t] : 0;
    s[t] = v;
    __syncthreads();
    for (int off = 1; off < 256; off <<= 1) {
        int tmp = (t >= off) ? s[t - off] : 0;
        __syncthreads();
        s[t] += tmp;
        __syncthreads();
    }
    int excl = s[t] - v;
    if (t < nbins) { binBase[t] = excl; binCur[t] = excl; }
    if (t == 0) { binBase[nbins] = E; offsets[n] = E; }
}

// ---------------------------------------------------------------- pass1 scatter: LDS-group by bin, contiguous runs
__global__ __launch_bounds__(256) void k_p1scatter(const int* __restrict__ row, const int* __restrict__ col,
                                                   int* __restrict__ binCur, unsigned* __restrict__ ebuf, int E) {
    __shared__ int h[256], s[256], lscan[256], delta[256], lcur[256];
    __shared__ unsigned stage[4096];
    int t = threadIdx.x;
    h[t] = 0;
    __syncthreads();
    int base = blockIdx.x * 4096;
    int cnt = min(4096, E - base);
#pragma unroll
    for (int k = 0; k < 16; ++k) {
        int e = base + k * 256 + t;
        if (e < E) atomicAdd(&h[col[e] >> 8], 1);
    }
    __syncthreads();
    int v = h[t];
    s[t] = v;
    __syncthreads();
    for (int off = 1; off < 256; off <<= 1) {
        int tmp = (t >= off) ? s[t - off] : 0;
        __syncthreads();
        s[t] += tmp;
        __syncthreads();
    }
    int excl = s[t] - v;
    lscan[t] = excl;
    lcur[t] = excl;
    delta[t] = (v > 0) ? (atomicAdd(&binCur[t], v) - excl) : 0;
    __syncthreads();
#pragma unroll
    for (int k = 0; k < 16; ++k) {
        int e = base + k * 256 + t;
        if (e < E) {
            int d = col[e];
            int slot = atomicAdd(&lcur[d >> 8], 1);
            stage[slot] = ((unsigned)d << 16) | (unsigned)row[e];   // n < 2^16: both fit
        }
    }
    __syncthreads();
#pragma unroll
    for (int k = 0; k < 16; ++k) {
        int slot = k * 256 + t;
        if (slot < cnt) {
            unsigned vv = stage[slot];
            int b = vv >> 24;
            ebuf[delta[b] + slot] = vv;
        }
    }
}

// ---------------------------------------------------------------- pass2: per-bin exact counting sort
__global__ __launch_bounds__(256) void k_p2sort(const unsigned* __restrict__ ebuf, const int* __restrict__ binBase,
                                                int* __restrict__ csr, int* __restrict__ offsets,
                                                float* __restrict__ dinv, int n) {
    __shared__ unsigned stage[P2CAP];
    __shared__ unsigned stage2[P2CAP];
    __shared__ int h[256], s[256], cur[256];
    int b = blockIdx.x, t = threadIdx.x;
    int beg = binBase[b], end = binBase[b + 1];
    int cnt = end - beg;
    h[t] = 0;
    __syncthreads();
    for (int i = t; i < cnt; i += 256) {
        unsigned v = ebuf[beg + i];
        stage[i] = v;
        atomicAdd(&h[(v >> 16) & 0xFF], 1);
    }
    __syncthreads();
    int v = h[t];
    s[t] = v;
    __syncthreads();
    for (int off = 1; off < 256; off <<= 1) {
        int tmp = (t >= off) ? s[t - off] : 0;
        __syncthreads();
        s[t] += tmp;
        __syncthreads();
    }
    int excl = s[t] - v;
    cur[t] = excl;
    int d = b * 256 + t;
    if (d < n) {
        offsets[d] = beg + excl;
        dinv[d] = rsqrtf((float)(v + 1));           // +1 self-loop
    }
    __syncthreads();
    for (int i = t; i < cnt; i += 256) {
        unsigned vv = stage[i];
        int slot = atomicAdd(&cur[(vv >> 16) & 0xFF], 1);
        stage2[slot] = vv & 0xFFFFu;
    }
    __syncthreads();
    for (int i = t; i < cnt; i += 256) csr[beg + i] = (int)stage2[i];
}

// ---------------------------------------------------------------- pack W0 / W1 / biases
__global__ __launch_bounds__(256) void k_packW(const float* __restrict__ w0, const float* __restrict__ w1,
                                               const float* __restrict__ b0, const float* __restrict__ b1,
                                               uint4* __restrict__ Wp0, uint4* __restrict__ Wp1,
                                               float* __restrict__ b0p, float* __restrict__ b1p) {
    int t = threadIdx.x;
    for (int e = t; e < 2048; e += 256) {
        int l = e & 63, U = (e >> 6) & 7, T = e >> 9;
        int nn = U * 16 + (l & 15);
        int kq = T * 32 + ((l >> 4) << 3);
        unsigned r[4], s[4];
#pragma unroll
        for (int jj = 0; jj < 4; ++jj) {
            int k0 = kq + 2 * jj, k1 = k0 + 1;
            unsigned a0 = f2bf(w0[k0 * 128 + nn]), a1 = f2bf(w0[k1 * 128 + nn]);
            r[jj] = a0 | (a1 << 16);
            int c0 = ((k0 & 7) << 4) | (k0 >> 3), c1 = ((k1 & 7) << 4) | (k1 >> 3);
            unsigned q0 = f2bf(w1[c0 * 128 + nn]), q1 = f2bf(w1[c1 * 128 + nn]);
            s[jj] = q0 | (q1 << 16);
        }
        Wp0[e] = make_uint4(r[0], r[1], r[2], r[3]);
        Wp1[e] = make_uint4(s[0], s[1], s[2], s[3]);
    }
    if (t < 128) {
        int c = ((t & 7) << 4) | (t >> 3);
        b0p[t] = b0[c];
        b1p[t] = b1[c];
    }
}

// ---------------------------------------------------------------- MFMA GEMM, fp32 input (conv0)
__global__ __launch_bounds__(256) void k_gemm0(const float* __restrict__ x, const uint4* __restrict__ Wp,
                                               const float* __restrict__ dinv, unsigned* __restrict__ outb, int n) {
    int wave = threadIdx.x >> 6, l = threadIdx.x & 63;
    int mt = blockIdx.x * 4 + wave;
    int r0 = mt * 16;
    if (r0 >= n) return;
    int rowA = r0 + (l & 15);
    int kq = (l >> 4) * 8;
    f32x4 acc[8];
#pragma unroll
    for (int U = 0; U < 8; ++U) acc[U] = (f32x4){0.f, 0.f, 0.f, 0.f};
    const float* xr = x + (size_t)rowA * 128 + kq;
#pragma unroll
    for (int T = 0; T < 4; ++T) {
        float4 a0 = *(const float4*)(xr + T * 32);
        float4 a1 = *(const float4*)(xr + T * 32 + 4);
        short8 af;
        af[0] = (short)f2bf(a0.x); af[1] = (short)f2bf(a0.y);
        af[2] = (short)f2bf(a0.z); af[3] = (short)f2bf(a0.w);
        af[4] = (short)f2bf(a1.x); af[5] = (short)f2bf(a1.y);
        af[6] = (short)f2bf(a1.z); af[7] = (short)f2bf(a1.w);
#pragma unroll
        for (int U = 0; U < 8; ++U) {
            short8 bf = *(const short8*)&Wp[(T * 8 + U) * 64 + l];
            acc[U] = __builtin_amdgcn_mfma_f32_16x16x32_bf16(af, bf, acc[U], 0, 0, 0);
        }
    }
    int rq = l >> 4, cl = l & 15;
#pragma unroll
    for (int q = 0; q < 4; ++q) {
        int rr = r0 + rq * 4 + q;
        float d = dinv[rr];
        uint4 w;
        w.x = (unsigned)f2bf(acc[0][q] * d) | ((unsigned)f2bf(acc[1][q] * d) << 16);
        w.y = (unsigned)f2bf(acc[2][q] * d) | ((unsigned)f2bf(acc[3][q] * d) << 16);
        w.z = (unsigned)f2bf(acc[4][q] * d) | ((unsigned)f2bf(acc[5][q] * d) << 16);
        w.w = (unsigned)f2bf(acc[6][q] * d) | ((unsigned)f2bf(acc[7][q] * d) << 16);
        *(uint4*)(outb + (size_t)rr * 64 + cl * 4) = w;
    }
}

// ---------------------------------------------------------------- MFMA GEMM, bf16 P1 input (conv1)
__global__ __launch_bounds__(256) void k_gemm1(const unsigned* __restrict__ inb, const uint4* __restrict__ Wp,
                                               const float* __restrict__ dinv, unsigned* __restrict__ outb, int n) {
    int wave = threadIdx.x >> 6, l = threadIdx.x & 63;
    int mt = blockIdx.x * 4 + wave;
    int r0 = mt * 16;
    if (r0 >= n) return;
    int rowA = r0 + (l & 15);
    int kq4 = (l >> 4) * 4;
    f32x4 acc[8];
#pragma unroll
    for (int U = 0; U < 8; ++U) acc[U] = (f32x4){0.f, 0.f, 0.f, 0.f};
    const unsigned* ir = inb + (size_t)rowA * 64 + kq4;
#pragma unroll
    for (int T = 0; T < 4; ++T) {
        short8 af = *(const short8*)(ir + T * 16);
#pragma unroll
        for (int U = 0; U < 8; ++U) {
            short8 bf = *(const short8*)&Wp[(T * 8 + U) * 64 + l];
            acc[U] = __builtin_amdgcn_mfma_f32_16x16x32_bf16(af, bf, acc[U], 0, 0, 0);
        }
    }
    int rq = l >> 4, cl = l & 15;
#pragma unroll
    for (int q = 0; q < 4; ++q) {
        int rr = r0 + rq * 4 + q;
        float d = dinv[rr];
        uint4 w;
        w.x = (unsigned)f2bf(acc[0][q] * d) | ((unsigned)f2bf(acc[1][q] * d) << 16);
        w.y = (unsigned)f2bf(acc[2][q] * d) | ((unsigned)f2bf(acc[3][q] * d) << 16);
        w.z = (unsigned)f2bf(acc[4][q] * d) | ((unsigned)f2bf(acc[5][q] * d) << 16);
        w.w = (unsigned)f2bf(acc[6][q] * d) | ((unsigned)f2bf(acc[7][q] * d) << 16);
        *(uint4*)(outb + (size_t)rr * 64 + cl * 4) = w;
    }
}

// ---------------------------------------------------------------- wide gather core: 16 lanes/row, dwordx4
// Wave covers 4 edges per instruction (group g = l>>4), lane handles quarter-row q = l&15.
// acc[k] accumulates position 8q+k (fp32). Caller must butterfly-reduce over g afterwards.
__device__ inline void gather16(const uint4* __restrict__ hp4, const int* __restrict__ src,
                                int g, int q, int beg, int end, float acc[8]) {
    int e = beg;
    while (e + 8 <= end) {                      // two full groups of 4
        int s0 = src[e + g];
        int s1 = src[e + 4 + g];
        uint4 u0 = hp4[(size_t)s0 * 16 + q];
        uint4 u1 = hp4[(size_t)s1 * 16 + q];
        acc[0] += bflo(u0.x) + bflo(u1.x); acc[1] += bfhi(u0.x) + bfhi(u1.x);
        acc[2] += bflo(u0.y) + bflo(u1.y); acc[3] += bfhi(u0.y) + bfhi(u1.y);
        acc[4] += bflo(u0.z) + bflo(u1.z); acc[5] += bfhi(u0.z) + bfhi(u1.z);
        acc[6] += bflo(u0.w) + bflo(u1.w); acc[7] += bfhi(u0.w) + bfhi(u1.w);
        e += 8;
    }
    while (e < end) {                           // remainder groups (partial)
        int i = e + g;
        int si = src[(i < end) ? i : e];        // e < end here, safe
        uint4 u = hp4[(size_t)si * 16 + q];
        if (i < end) {
            acc[0] += bflo(u.x); acc[1] += bfhi(u.x);
            acc[2] += bflo(u.y); acc[3] += bfhi(u.y);
            acc[4] += bflo(u.z); acc[5] += bfhi(u.z);
            acc[6] += bflo(u.w); acc[7] += bfhi(u.w);
        }
        e += 4;
    }
    // reduce across the 4 groups (lanes l, l^16, l^32, l^48)
#pragma unroll
    for (int k = 0; k < 8; ++k) {
        acc[k] += __shfl_xor(acc[k], 16, 64);
        acc[k] += __shfl_xor(acc[k], 32, 64);
    }
}

// ---------------------------------------------------------------- agg conv0
__global__ __launch_bounds__(256) void k_agg0(const unsigned* __restrict__ hp, const int* __restrict__ offs,
                                              const int* __restrict__ src, const float* __restrict__ dinv,
                                              const float* __restrict__ bp, unsigned* __restrict__ outb, int n) {
    int wid = (blockIdx.x * 256 + threadIdx.x) >> 6;
    int l = threadIdx.x & 63;
    if (wid >= n) return;
    int g = l >> 4, q = l & 15;
    const uint4* hp4 = (const uint4*)hp;
    float acc[8] = {0, 0, 0, 0, 0, 0, 0, 0};
    {   // self-loop: group 0 only
        uint4 us = hp4[(size_t)wid * 16 + q];
        if (g == 0) {
            acc[0] = bflo(us.x); acc[1] = bfhi(us.x);
            acc[2] = bflo(us.y); acc[3] = bfhi(us.y);
            acc[4] = bflo(us.z); acc[5] = bfhi(us.z);
            acc[6] = bflo(us.w); acc[7] = bfhi(us.w);
        }
    }
    gather16(hp4, src, g, q, offs[wid], offs[wid + 1], acc);
    float d = dinv[wid];
    const float4* bp4 = (const float4*)bp;
    float4 ba = bp4[q * 2], bb = bp4[q * 2 + 1];
    float o0 = fmaxf(fmaf(d, acc[0], ba.x), 0.f), o1 = fmaxf(fmaf(d, acc[1], ba.y), 0.f);
    float o2 = fmaxf(fmaf(d, acc[2], ba.z), 0.f), o3 = fmaxf(fmaf(d, acc[3], ba.w), 0.f);
    float o4 = fmaxf(fmaf(d, acc[4], bb.x), 0.f), o5 = fmaxf(fmaf(d, acc[5], bb.y), 0.f);
    float o6 = fmaxf(fmaf(d, acc[6], bb.z), 0.f), o7 = fmaxf(fmaf(d, acc[7], bb.w), 0.f);
    if (g == 0) {
        uint4 w;
        w.x = (unsigned)f2bf(o0) | ((unsigned)f2bf(o1) << 16);
        w.y = (unsigned)f2bf(o2) | ((unsigned)f2bf(o3) << 16);
        w.z = (unsigned)f2bf(o4) | ((unsigned)f2bf(o5) << 16);
        w.w = (unsigned)f2bf(o6) | ((unsigned)f2bf(o7) << 16);
        ((uint4*)outb)[(size_t)wid * 16 + q] = w;
    }
}

// ---------------------------------------------------------------- agg conv1 + fused segment-max pool
__global__ __launch_bounds__(256) void k_agg1(const unsigned* __restrict__ hp, const int* __restrict__ offs,
                                              const int* __restrict__ src, const float* __restrict__ dinv,
                                              const float* __restrict__ bp, const int* __restrict__ batch,
                                              int* __restrict__ pool, int n) {
    __shared__ float2 sv[4][64];
    __shared__ int sg[4];
    int w = threadIdx.x >> 6, l = threadIdx.x & 63;
    int wid = blockIdx.x * 4 + w;
    int g = l >> 4, q = l & 15;
    if (wid < n) {
        const uint4* hp4 = (const uint4*)hp;
        float acc[8] = {0, 0, 0, 0, 0, 0, 0, 0};
        {
            uint4 us = hp4[(size_t)wid * 16 + q];
            if (g == 0) {
                acc[0] = bflo(us.x); acc[1] = bfhi(us.x);
                acc[2] = bflo(us.y); acc[3] = bfhi(us.y);
                acc[4] = bflo(us.z); acc[5] = bfhi(us.z);
                acc[6] = bflo(us.w); acc[7] = bfhi(us.w);
            }
        }
        gather16(hp4, src, g, q, offs[wid], offs[wid + 1], acc);
        float d = dinv[wid];
        const float4* bp4 = (const float4*)bp;
        float4 ba = bp4[q * 2], bb = bp4[q * 2 + 1];
        if (g == 0) {
            sv[w][q * 4 + 0] = make_float2(fmaxf(fmaf(d, acc[0], ba.x), 0.f), fmaxf(fmaf(d, acc[1], ba.y), 0.f));
            sv[w][q * 4 + 1] = make_float2(fmaxf(fmaf(d, acc[2], ba.z), 0.f), fmaxf(fmaf(d, acc[3], ba.w), 0.f));
            sv[w][q * 4 + 2] = make_float2(fmaxf(fmaf(d, acc[4], bb.x), 0.f), fmaxf(fmaf(d, acc[5], bb.y), 0.f));
            sv[w][q * 4 + 3] = make_float2(fmaxf(fmaf(d, acc[6], bb.z), 0.f), fmaxf(fmaf(d, acc[7], bb.w), 0.f));
            if (q == 0) sg[w] = batch[wid];
        }
    } else if (l == 0) {
        sg[w] = -1;
    }
    __syncthreads();
    if (threadIdx.x < 64) {
        int t = threadIdx.x;
        int c0 = 32 * (t & 3) + (t >> 2);           // true col of position 2t; pair col = c0+16
        int cur = sg[0];
        float2 m = sv[0][t];
        for (int ww = 1; ww < 4; ++ww) {
            int gg = sg[ww];
            if (gg < 0) break;                      // batch sorted; invalid only at tail
            float2 v = sv[ww][t];
            if (gg == cur) { m.x = fmaxf(m.x, v.x); m.y = fmaxf(m.y, v.y); }
            else {
                atomicMax(&pool[cur * 128 + c0], __float_as_int(m.x));
                atomicMax(&pool[cur * 128 + c0 + 16], __float_as_int(m.y));
                cur = gg; m = v;
            }
        }
        atomicMax(&pool[cur * 128 + c0], __float_as_int(m.x));
        atomicMax(&pool[cur * 128 + c0 + 16], __float_as_int(m.y));
    }
}

// ---------------------------------------------------------------- final MLP + log_softmax, 1 block/graph
__global__ __launch_bounds__(128) void k_mlp(const float* __restrict__ pool, const float* __restrict__ W0,
                                             const float* __restrict__ b0, const float* __restrict__ W1,
                                             const float* __restrict__ b1, float* __restrict__ out) {
    __shared__ float rowv[128];
    __shared__ float h2[128];
    __shared__ float h3[10];
    int g = blockIdx.x, t = threadIdx.x;
    rowv[t] = pool[g * 128 + t];
    __syncthreads();
    float acc = b0[t];
    for (int k = 0; k < 128; ++k) acc = fmaf(rowv[k], W0[k * 128 + t], acc);
    h2[t] = fmaxf(acc, 0.f);
    __syncthreads();
    if (t < 10) {
        float a = b1[t];
        for (int k = 0; k < 128; ++k) a = fmaf(h2[k], W1[k * 10 + t], a);
        h3[t] = fmaxf(a, 0.f);
    }
    __syncthreads();
    if (t == 0) {
        float mx = h3[0];
        for (int j = 1; j < 10; ++j) mx = fmaxf(mx, h3[j]);
        float s = 0.f;
        for (int j = 0; j < 10; ++j) s += expf(h3[j] - mx);
        float lse = logf(s) + mx;
        for (int j = 0; j < 10; ++j) out[g * 10 + j] = h3[j] - lse;
    }
}

// ----------------------------------------------------------------
extern "C" void kernel_launch(void* const* d_in, const int* in_sizes, int n_in,
                              void* d_out, int out_size, void* d_ws, size_t ws_size,
                              hipStream_t stream) {
    const float* x   = (const float*)d_in[0];
    const int* eidx  = (const int*)d_in[1];
    const int* batch = (const int*)d_in[2];
    const float* w0  = (const float*)d_in[3];
    const float* b0  = (const float*)d_in[4];
    const float* w1  = (const float*)d_in[5];
    const float* b1  = (const float*)d_in[6];
    const float* lw0 = (const float*)d_in[7];
    const float* lb0 = (const float*)d_in[8];
    const float* lw1 = (const float*)d_in[9];
    const float* lb1 = (const float*)d_in[10];
    float* out = (float*)d_out;

    int n = in_sizes[2];
    int E = in_sizes[1] / 2;
    const int* row = eidx;        // sources
    const int* col = eidx + E;    // destinations
    int nbins = (n + 255) >> 8;   // 196 coarse bins (n < 2^16 required for packing)
    int nb1 = (E + 4095) / 4096;  // pass-1 blocks

    char* ws = (char*)d_ws;
    size_t o = 0;
    auto take = [&](size_t bytes) { void* p = ws + o; o += (bytes + 255) & ~(size_t)255; return p; };
    int*      binCnt   = (int*)     take(256 * 4);
    int*      binBase  = (int*)     take(260 * 4);
    int*      binCur   = (int*)     take(256 * 4);
    int*      offsets  = (int*)     take((size_t)(n + 1) * 4);
    float*    dinv     = (float*)   take((size_t)n * 4);
    int*      csr      = (int*)     take((size_t)E * 4);
    unsigned* ebuf     = (unsigned*)take((size_t)E * 4);
    uint4*    Wp0      = (uint4*)   take(2048 * 16);
    uint4*    Wp1      = (uint4*)   take(2048 * 16);
    float*    b0p      = (float*)   take(128 * 4);
    float*    b1p      = (float*)   take(128 * 4);
    unsigned* h0b      = (unsigned*)take((size_t)n * 64 * 4);   // bf16 P1 rows
    unsigned* h1i      = (unsigned*)take((size_t)n * 64 * 4);
    unsigned* h1b      = (unsigned*)take((size_t)n * 64 * 4);
    int*      pool     = (int*)     take(64 * 128 * 4);

    hipMemsetAsync(binCnt, 0, 256 * 4, stream);
    hipMemsetAsync(pool, 0, 64 * 128 * 4, stream);

    // CSR build: 2-pass LDS-staged bucket sort (no fine-grained global scatter)
    k_p1hist<<<nb1, 256, 0, stream>>>(col, binCnt, E);
    k_binscan<<<1, 256, 0, stream>>>(binCnt, binBase, binCur, offsets, nbins, n, E);
    k_p1scatter<<<nb1, 256, 0, stream>>>(row, col, binCur, ebuf, E);
    k_p2sort<<<nbins, 256, 0, stream>>>(ebuf, binBase, csr, offsets, dinv, n);

    k_packW<<<1, 256, 0, stream>>>(w0, w1, b0, b1, Wp0, Wp1, b0p, b1p);

    int mtBlocks = ((n + 15) / 16 + 3) / 4;     // 4 waves/block, 1 mtile/wave

    // conv0
    k_gemm0<<<mtBlocks, 256, 0, stream>>>(x, Wp0, dinv, h0b, n);
    k_agg0<<<(n + 3) / 4, 256, 0, stream>>>(h0b, offsets, csr, dinv, b0p, h1i, n);
    // conv1 (+ fused pool)
    k_gemm1<<<mtBlocks, 256, 0, stream>>>(h1i, Wp1, dinv, h1b, n);
    k_agg1<<<(n + 3) / 4, 256, 0, stream>>>(h1b, offsets, csr, dinv, b1p, batch, pool, n);

    k_mlp<<<64, 128, 0, stream>>>((const float*)pool, lw0, lb0, lw1, lb1, out);
}

// Round 10
// 227.322 us; speedup vs baseline: 1.7655x; 1.0468x over previous
//
#include <hip/hip_runtime.h>

#define D 128
#define BINCAP 6144
#define P2CAP 6144

typedef __attribute__((ext_vector_type(8))) short short8;
typedef __attribute__((ext_vector_type(4))) float f32x4;

__device__ inline unsigned short f2bf(float f) {
    unsigned u = __float_as_uint(f);
    return (unsigned short)((u + 0x7FFFu + ((u >> 16) & 1u)) >> 16);
}
__device__ inline float bflo(unsigned u) { return __uint_as_float(u << 16); }
__device__ inline float bfhi(unsigned u) { return __uint_as_float(u & 0xFFFF0000u); }

// ---------------------------------------------------------------- init: bin cursors + pool zero + packW + biases
// P1 position->col: c(p) = (p&7)*16 + (p>>3).
__global__ __launch_bounds__(256) void k_init(const float* __restrict__ w0, const float* __restrict__ w1,
                                              const float* __restrict__ b0, const float* __restrict__ b1,
                                              uint4* __restrict__ Wp0, uint4* __restrict__ Wp1,
                                              float* __restrict__ b0p, float* __restrict__ b1p,
                                              int* __restrict__ binCur, int* __restrict__ pool, int nbins) {
    int t = threadIdx.x;
    if (t < nbins) binCur[t] = t * BINCAP;
    for (int i = t; i < 64 * 128; i += 256) pool[i] = 0;
    for (int e = t; e < 2048; e += 256) {
        int l = e & 63, U = (e >> 6) & 7, T = e >> 9;
        int nn = U * 16 + (l & 15);
        int kq = T * 32 + ((l >> 4) << 3);
        unsigned r[4], s[4];
#pragma unroll
        for (int jj = 0; jj < 4; ++jj) {
            int k0 = kq + 2 * jj, k1 = k0 + 1;
            unsigned a0 = f2bf(w0[k0 * 128 + nn]), a1 = f2bf(w0[k1 * 128 + nn]);
            r[jj] = a0 | (a1 << 16);
            int c0 = ((k0 & 7) << 4) | (k0 >> 3), c1 = ((k1 & 7) << 4) | (k1 >> 3);
            unsigned q0 = f2bf(w1[c0 * 128 + nn]), q1 = f2bf(w1[c1 * 128 + nn]);
            s[jj] = q0 | (q1 << 16);
        }
        Wp0[e] = make_uint4(r[0], r[1], r[2], r[3]);
        Wp1[e] = make_uint4(s[0], s[1], s[2], s[3]);
    }
    if (t < 128) {
        int c = ((t & 7) << 4) | (t >> 3);
        b0p[t] = b0[c];
        b1p[t] = b1[c];
    }
}

// ---------------------------------------------------------------- pass1 scatter into strided bins (LDS-grouped runs)
__global__ __launch_bounds__(256) void k_p1scatter(const int* __restrict__ row, const int* __restrict__ col,
                                                   int* __restrict__ binCur, unsigned* __restrict__ ebuf, int E) {
    __shared__ int h[256], s[256], delta[256], lcur[256];
    __shared__ unsigned stage[4096];
    int t = threadIdx.x;
    h[t] = 0;
    __syncthreads();
    int base = blockIdx.x * 4096;
    int cnt = min(4096, E - base);
#pragma unroll
    for (int k = 0; k < 16; ++k) {
        int e = base + k * 256 + t;
        if (e < E) atomicAdd(&h[col[e] >> 8], 1);
    }
    __syncthreads();
    int v = h[t];
    s[t] = v;
    __syncthreads();
    for (int off = 1; off < 256; off <<= 1) {
        int tmp = (t >= off) ? s[t - off] : 0;
        __syncthreads();
        s[t] += tmp;
        __syncthreads();
    }
    int excl = s[t] - v;
    lcur[t] = excl;
    delta[t] = (v > 0) ? (atomicAdd(&binCur[t], v) - excl) : 0;
    __syncthreads();
#pragma unroll
    for (int k = 0; k < 16; ++k) {
        int e = base + k * 256 + t;
        if (e < E) {
            int d = col[e];
            int slot = atomicAdd(&lcur[d >> 8], 1);
            stage[slot] = ((unsigned)d << 16) | (unsigned)row[e];   // n < 2^16: both fit
        }
    }
    __syncthreads();
#pragma unroll
    for (int k = 0; k < 16; ++k) {
        int slot = k * 256 + t;
        if (slot < cnt) {
            unsigned vv = stage[slot];
            int b = vv >> 24;
            ebuf[delta[b] + slot] = vv;
        }
    }
}

// ---------------------------------------------------------------- pass2: per-bin counting sort -> csr/off/end/dinv
__global__ __launch_bounds__(256) void k_p2sort(const unsigned* __restrict__ ebuf, const int* __restrict__ binCur,
                                                int* __restrict__ csr, int* __restrict__ off_, int* __restrict__ end_,
                                                float* __restrict__ dinv, int n) {
    __shared__ unsigned stage[P2CAP];
    __shared__ unsigned stage2[P2CAP];
    __shared__ int h[256], s[256], cur[256];
    int b = blockIdx.x, t = threadIdx.x;
    int beg = b * BINCAP;
    int cnt = binCur[b] - beg;
    h[t] = 0;
    __syncthreads();
    for (int i = t; i < cnt; i += 256) {
        unsigned v = ebuf[beg + i];
        stage[i] = v;
        atomicAdd(&h[(v >> 16) & 0xFF], 1);
    }
    __syncthreads();
    int v = h[t];
    s[t] = v;
    __syncthreads();
    for (int off = 1; off < 256; off <<= 1) {
        int tmp = (t >= off) ? s[t - off] : 0;
        __syncthreads();
        s[t] += tmp;
        __syncthreads();
    }
    int excl = s[t] - v;
    cur[t] = excl;
    int d = b * 256 + t;
    if (d < n) {
        off_[d] = beg + excl;
        end_[d] = beg + excl + v;
        dinv[d] = rsqrtf((float)(v + 1));           // +1 self-loop
    }
    __syncthreads();
    for (int i = t; i < cnt; i += 256) {
        unsigned vv = stage[i];
        int slot = atomicAdd(&cur[(vv >> 16) & 0xFF], 1);
        stage2[slot] = vv & 0xFFFFu;
    }
    __syncthreads();
    for (int i = t; i < cnt; i += 256) csr[beg + i] = (int)stage2[i];
}

// ---------------------------------------------------------------- MFMA GEMM, fp32 input (conv0), out bf16 P1 positions
__global__ __launch_bounds__(256) void k_gemm0(const float* __restrict__ x, const uint4* __restrict__ Wp,
                                               const float* __restrict__ dinv, unsigned* __restrict__ outb, int n) {
    int wave = threadIdx.x >> 6, l = threadIdx.x & 63;
    int mt = blockIdx.x * 4 + wave;
    int r0 = mt * 16;
    if (r0 >= n) return;
    int rowA = r0 + (l & 15);
    int kq = (l >> 4) * 8;
    f32x4 acc[8];
#pragma unroll
    for (int U = 0; U < 8; ++U) acc[U] = (f32x4){0.f, 0.f, 0.f, 0.f};
    const float* xr = x + (size_t)rowA * 128 + kq;
#pragma unroll
    for (int T = 0; T < 4; ++T) {
        float4 a0 = *(const float4*)(xr + T * 32);
        float4 a1 = *(const float4*)(xr + T * 32 + 4);
        short8 af;
        af[0] = (short)f2bf(a0.x); af[1] = (short)f2bf(a0.y);
        af[2] = (short)f2bf(a0.z); af[3] = (short)f2bf(a0.w);
        af[4] = (short)f2bf(a1.x); af[5] = (short)f2bf(a1.y);
        af[6] = (short)f2bf(a1.z); af[7] = (short)f2bf(a1.w);
#pragma unroll
        for (int U = 0; U < 8; ++U) {
            short8 bf = *(const short8*)&Wp[(T * 8 + U) * 64 + l];
            acc[U] = __builtin_amdgcn_mfma_f32_16x16x32_bf16(af, bf, acc[U], 0, 0, 0);
        }
    }
    int rq = l >> 4, cl = l & 15;
#pragma unroll
    for (int q = 0; q < 4; ++q) {
        int rr = r0 + rq * 4 + q;
        float d = dinv[rr];
        uint4 w;
        w.x = (unsigned)f2bf(acc[0][q] * d) | ((unsigned)f2bf(acc[1][q] * d) << 16);
        w.y = (unsigned)f2bf(acc[2][q] * d) | ((unsigned)f2bf(acc[3][q] * d) << 16);
        w.z = (unsigned)f2bf(acc[4][q] * d) | ((unsigned)f2bf(acc[5][q] * d) << 16);
        w.w = (unsigned)f2bf(acc[6][q] * d) | ((unsigned)f2bf(acc[7][q] * d) << 16);
        *(uint4*)(outb + (size_t)rr * 64 + cl * 4) = w;
    }
}

// ---------------------------------------------------------------- gather core: wave = 4 nodes, 16 lanes/node, dwordx4
// Lane (g=l>>4, q=l&15) accumulates positions 8q..8q+7 of node g. len uniform within a 16-lane group.
__device__ inline void gather4(const uint4* __restrict__ hp4, const int* __restrict__ csr,
                               int q, int beg, int len, float acc[8]) {
    int maxlen = len;
    maxlen = max(maxlen, __shfl_xor(maxlen, 16, 64));
    maxlen = max(maxlen, __shfl_xor(maxlen, 32, 64));
    int j = 0;
    for (; j + 2 <= maxlen; j += 2) {
        bool a0 = (j < len), a1 = (j + 1 < len);
        int s0 = 0, s1 = 0;
        if (a0) s0 = csr[beg + j];
        if (a1) s1 = csr[beg + j + 1];
        uint4 u0, u1;
        if (a0) u0 = hp4[(size_t)s0 * 16 + q];
        if (a1) u1 = hp4[(size_t)s1 * 16 + q];
        if (a0) {
            acc[0] += bflo(u0.x); acc[1] += bfhi(u0.x);
            acc[2] += bflo(u0.y); acc[3] += bfhi(u0.y);
            acc[4] += bflo(u0.z); acc[5] += bfhi(u0.z);
            acc[6] += bflo(u0.w); acc[7] += bfhi(u0.w);
        }
        if (a1) {
            acc[0] += bflo(u1.x); acc[1] += bfhi(u1.x);
            acc[2] += bflo(u1.y); acc[3] += bfhi(u1.y);
            acc[4] += bflo(u1.z); acc[5] += bfhi(u1.z);
            acc[6] += bflo(u1.w); acc[7] += bfhi(u1.w);
        }
    }
    for (; j < maxlen; ++j) {
        if (j < len) {
            int s0 = csr[beg + j];
            uint4 u = hp4[(size_t)s0 * 16 + q];
            acc[0] += bflo(u.x); acc[1] += bfhi(u.x);
            acc[2] += bflo(u.y); acc[3] += bfhi(u.y);
            acc[4] += bflo(u.z); acc[5] += bfhi(u.z);
            acc[6] += bflo(u.w); acc[7] += bfhi(u.w);
        }
    }
}

// ---------------------------------------------------------------- fused agg(conv0) + GEMM(conv1)
// Block = 16 nodes. Gather+relu+bias -> 4KB LDS bf16 tile -> MFMA vs Wp1 -> h1b (same layout as gemm output).
__global__ __launch_bounds__(256) void k_aggemm(const unsigned* __restrict__ hp, const int* __restrict__ off_,
                                                const int* __restrict__ end_, const int* __restrict__ csr,
                                                const float* __restrict__ dinv, const float* __restrict__ bp,
                                                const uint4* __restrict__ Wp, unsigned* __restrict__ outb, int n) {
    __shared__ uint4 sA[16 * 17];               // 16 rows x 16 uint4, pad 1 uint4/row
    int w = threadIdx.x >> 6, l = threadIdx.x & 63;
    int g = l >> 4, q = l & 15;
    int r0 = blockIdx.x * 16;
    int node = r0 + w * 4 + g;                  // n % 16 == 0
    const uint4* hp4 = (const uint4*)hp;
    float acc[8];
    uint4 us = hp4[(size_t)node * 16 + q];      // self-loop
    acc[0] = bflo(us.x); acc[1] = bfhi(us.x);
    acc[2] = bflo(us.y); acc[3] = bfhi(us.y);
    acc[4] = bflo(us.z); acc[5] = bfhi(us.z);
    acc[6] = bflo(us.w); acc[7] = bfhi(us.w);
    int beg = off_[node];
    int len = end_[node] - beg;
    gather4(hp4, csr, q, beg, len, acc);
    float d0 = dinv[node];
    const float4* bp4 = (const float4*)bp;
    float4 ba = bp4[q * 2], bb = bp4[q * 2 + 1];
    uint4 pk;
    pk.x = (unsigned)f2bf(fmaxf(fmaf(d0, acc[0], ba.x), 0.f)) | ((unsigned)f2bf(fmaxf(fmaf(d0, acc[1], ba.y), 0.f)) << 16);
    pk.y = (unsigned)f2bf(fmaxf(fmaf(d0, acc[2], ba.z), 0.f)) | ((unsigned)f2bf(fmaxf(fmaf(d0, acc[3], ba.w), 0.f)) << 16);
    pk.z = (unsigned)f2bf(fmaxf(fmaf(d0, acc[4], bb.x), 0.f)) | ((unsigned)f2bf(fmaxf(fmaf(d0, acc[5], bb.y), 0.f)) << 16);
    pk.w = (unsigned)f2bf(fmaxf(fmaf(d0, acc[6], bb.z), 0.f)) | ((unsigned)f2bf(fmaxf(fmaf(d0, acc[7], bb.w), 0.f)) << 16);
    sA[(w * 4 + g) * 17 + q] = pk;
    __syncthreads();
    // MFMA: wave w computes column tiles U = 2w, 2w+1
    int rq = l >> 4, cl = l & 15;
    f32x4 c0v = (f32x4){0.f, 0.f, 0.f, 0.f}, c1v = (f32x4){0.f, 0.f, 0.f, 0.f};
#pragma unroll
    for (int T = 0; T < 4; ++T) {
        short8 af = *(const short8*)&sA[(l & 15) * 17 + T * 4 + rq];
        short8 bf0 = *(const short8*)&Wp[(T * 8 + 2 * w) * 64 + l];
        short8 bf1 = *(const short8*)&Wp[(T * 8 + 2 * w + 1) * 64 + l];
        c0v = __builtin_amdgcn_mfma_f32_16x16x32_bf16(af, bf0, c0v, 0, 0, 0);
        c1v = __builtin_amdgcn_mfma_f32_16x16x32_bf16(af, bf1, c1v, 0, 0, 0);
    }
#pragma unroll
    for (int qq = 0; qq < 4; ++qq) {
        int rr = r0 + rq * 4 + qq;
        float d2 = dinv[rr];
        unsigned pkk = (unsigned)f2bf(c0v[qq] * d2) | ((unsigned)f2bf(c1v[qq] * d2) << 16);
        outb[(size_t)rr * 64 + cl * 4 + w] = pkk;   // dword cl*4+w = U pair (2w, 2w+1)
    }
}

// ---------------------------------------------------------------- agg conv1 + fused segment-max pool (16 nodes/block)
__global__ __launch_bounds__(256) void k_agg1(const unsigned* __restrict__ hp, const int* __restrict__ off_,
                                              const int* __restrict__ end_, const int* __restrict__ csr,
                                              const float* __restrict__ dinv, const float* __restrict__ bp,
                                              const int* __restrict__ batch, int* __restrict__ pool, int n) {
    __shared__ float2 sv[16][64];
    __shared__ int sg[16];
    int w = threadIdx.x >> 6, l = threadIdx.x & 63;
    int g = l >> 4, q = l & 15;
    int node = blockIdx.x * 16 + w * 4 + g;     // n % 16 == 0
    const uint4* hp4 = (const uint4*)hp;
    float acc[8];
    uint4 us = hp4[(size_t)node * 16 + q];
    acc[0] = bflo(us.x); acc[1] = bfhi(us.x);
    acc[2] = bflo(us.y); acc[3] = bfhi(us.y);
    acc[4] = bflo(us.z); acc[5] = bfhi(us.z);
    acc[6] = bflo(us.w); acc[7] = bfhi(us.w);
    int beg = off_[node];
    int len = end_[node] - beg;
    gather4(hp4, csr, q, beg, len, acc);
    float d0 = dinv[node];
    const float4* bp4 = (const float4*)bp;
    float4 ba = bp4[q * 2], bb = bp4[q * 2 + 1];
    int rowi = w * 4 + g;
    sv[rowi][q * 4 + 0] = make_float2(fmaxf(fmaf(d0, acc[0], ba.x), 0.f), fmaxf(fmaf(d0, acc[1], ba.y), 0.f));
    sv[rowi][q * 4 + 1] = make_float2(fmaxf(fmaf(d0, acc[2], ba.z), 0.f), fmaxf(fmaf(d0, acc[3], ba.w), 0.f));
    sv[rowi][q * 4 + 2] = make_float2(fmaxf(fmaf(d0, acc[4], bb.x), 0.f), fmaxf(fmaf(d0, acc[5], bb.y), 0.f));
    sv[rowi][q * 4 + 3] = make_float2(fmaxf(fmaf(d0, acc[6], bb.z), 0.f), fmaxf(fmaf(d0, acc[7], bb.w), 0.f));
    if (q == 0) sg[rowi] = batch[node];
    __syncthreads();
    if (threadIdx.x < 64) {
        int t = threadIdx.x;
        int c0 = 32 * (t & 3) + (t >> 2);       // true col of position 2t; pair col = c0+16
        int cur = sg[0];
        float2 m = sv[0][t];
        for (int ww = 1; ww < 16; ++ww) {
            int gg = sg[ww];
            float2 vv = sv[ww][t];
            if (gg == cur) { m.x = fmaxf(m.x, vv.x); m.y = fmaxf(m.y, vv.y); }
            else {
                atomicMax(&pool[cur * 128 + c0], __float_as_int(m.x));
                atomicMax(&pool[cur * 128 + c0 + 16], __float_as_int(m.y));
                cur = gg; m = vv;
            }
        }
        atomicMax(&pool[cur * 128 + c0], __float_as_int(m.x));
        atomicMax(&pool[cur * 128 + c0 + 16], __float_as_int(m.y));
    }
}

// ---------------------------------------------------------------- final MLP + log_softmax, 1 block/graph
__global__ __launch_bounds__(128) void k_mlp(const float* __restrict__ pool, const float* __restrict__ W0,
                                             const float* __restrict__ b0, const float* __restrict__ W1,
                                             const float* __restrict__ b1, float* __restrict__ out) {
    __shared__ float rowv[128];
    __shared__ float h2[128];
    __shared__ float h3[10];
    int g = blockIdx.x, t = threadIdx.x;
    rowv[t] = pool[g * 128 + t];
    __syncthreads();
    float acc = b0[t];
    for (int k = 0; k < 128; ++k) acc = fmaf(rowv[k], W0[k * 128 + t], acc);
    h2[t] = fmaxf(acc, 0.f);
    __syncthreads();
    if (t < 10) {
        float a = b1[t];
        for (int k = 0; k < 128; ++k) a = fmaf(h2[k], W1[k * 10 + t], a);
        h3[t] = fmaxf(a, 0.f);
    }
    __syncthreads();
    if (t == 0) {
        float mx = h3[0];
        for (int j = 1; j < 10; ++j) mx = fmaxf(mx, h3[j]);
        float s = 0.f;
        for (int j = 0; j < 10; ++j) s += expf(h3[j] - mx);
        float lse = logf(s) + mx;
        for (int j = 0; j < 10; ++j) out[g * 10 + j] = h3[j] - lse;
    }
}

// ----------------------------------------------------------------
extern "C" void kernel_launch(void* const* d_in, const int* in_sizes, int n_in,
                              void* d_out, int out_size, void* d_ws, size_t ws_size,
                              hipStream_t stream) {
    const float* x   = (const float*)d_in[0];
    const int* eidx  = (const int*)d_in[1];
    const int* batch = (const int*)d_in[2];
    const float* w0  = (const float*)d_in[3];
    const float* b0  = (const float*)d_in[4];
    const float* w1  = (const float*)d_in[5];
    const float* b1  = (const float*)d_in[6];
    const float* lw0 = (const float*)d_in[7];
    const float* lb0 = (const float*)d_in[8];
    const float* lw1 = (const float*)d_in[9];
    const float* lb1 = (const float*)d_in[10];
    float* out = (float*)d_out;

    int n = in_sizes[2];
    int E = in_sizes[1] / 2;
    const int* row = eidx;        // sources
    const int* col = eidx + E;    // destinations
    int nbins = (n + 255) >> 8;   // 196 (n < 2^16 required for packing)
    int nb1 = (E + 4095) / 4096;

    char* ws = (char*)d_ws;
    size_t o = 0;
    auto take = [&](size_t bytes) { void* p = ws + o; o += (bytes + 255) & ~(size_t)255; return p; };
    int*      binCur   = (int*)     take(256 * 4);
    int*      off_     = (int*)     take((size_t)n * 4);
    int*      end_     = (int*)     take((size_t)n * 4);
    float*    dinv     = (float*)   take((size_t)n * 4);
    int*      csr      = (int*)     take(((size_t)nbins * BINCAP + 64) * 4);
    unsigned* ebuf     = (unsigned*)take(((size_t)nbins * BINCAP + 64) * 4);
    uint4*    Wp0      = (uint4*)   take(2048 * 16);
    uint4*    Wp1      = (uint4*)   take(2048 * 16);
    float*    b0p      = (float*)   take(128 * 4);
    float*    b1p      = (float*)   take(128 * 4);
    unsigned* h0b      = (unsigned*)take((size_t)n * 64 * 4);   // bf16 P1 rows
    unsigned* h1b      = (unsigned*)take((size_t)n * 64 * 4);
    int*      pool     = (int*)     take(64 * 128 * 4);

    k_init<<<1, 256, 0, stream>>>(w0, w1, b0, b1, Wp0, Wp1, b0p, b1p, binCur, pool, nbins);
    k_p1scatter<<<nb1, 256, 0, stream>>>(row, col, binCur, ebuf, E);
    k_p2sort<<<nbins, 256, 0, stream>>>(ebuf, binCur, csr, off_, end_, dinv, n);

    int mtBlocks = ((n + 15) / 16 + 3) / 4;

    k_gemm0<<<mtBlocks, 256, 0, stream>>>(x, Wp0, dinv, h0b, n);
    k_aggemm<<<n / 16, 256, 0, stream>>>(h0b, off_, end_, csr, dinv, b0p, Wp1, h1b, n);
    k_agg1<<<n / 16, 256, 0, stream>>>(h1b, off_, end_, csr, dinv, b1p, batch, pool, n);
    k_mlp<<<64, 128, 0, stream>>>((const float*)pool, lw0, lb0, lw1, lb1, out);
}

// Round 11
// 209.180 us; speedup vs baseline: 1.9186x; 1.0867x over previous
//
#include <hip/hip_runtime.h>

#define D 128
#define BINCAP 6144
#define P2CAP 6144

typedef __attribute__((ext_vector_type(8))) short short8;
typedef __attribute__((ext_vector_type(4))) float f32x4;

__device__ inline unsigned short f2bf(float f) {
    unsigned u = __float_as_uint(f);
    return (unsigned short)((u + 0x7FFFu + ((u >> 16) & 1u)) >> 16);
}
__device__ inline float bflo(unsigned u) { return __uint_as_float(u << 16); }
__device__ inline float bfhi(unsigned u) { return __uint_as_float(u & 0xFFFF0000u); }

// ---------------------------------------------------------------- init (8 blocks): packW parallel + cursors + pool
// P1 position->col: c(p) = (p&7)*16 + (p>>3).
__global__ __launch_bounds__(256) void k_initW(const float* __restrict__ w0, const float* __restrict__ w1,
                                               const float* __restrict__ b0, const float* __restrict__ b1,
                                               uint4* __restrict__ Wp0, uint4* __restrict__ Wp1,
                                               float* __restrict__ b0p, float* __restrict__ b1p,
                                               int* __restrict__ binCur, int* __restrict__ pool, int nbins) {
    int t = threadIdx.x, b = blockIdx.x;
    int e = b * 256 + t;                        // 2048 elements over 8 blocks
    {
        int l = e & 63, U = (e >> 6) & 7, T = e >> 9;
        int nn = U * 16 + (l & 15);
        int kq = T * 32 + ((l >> 4) << 3);
        unsigned r[4], s[4];
#pragma unroll
        for (int jj = 0; jj < 4; ++jj) {
            int k0 = kq + 2 * jj, k1 = k0 + 1;
            unsigned a0 = f2bf(w0[k0 * 128 + nn]), a1 = f2bf(w0[k1 * 128 + nn]);
            r[jj] = a0 | (a1 << 16);
            int c0 = ((k0 & 7) << 4) | (k0 >> 3), c1 = ((k1 & 7) << 4) | (k1 >> 3);
            unsigned q0 = f2bf(w1[c0 * 128 + nn]), q1 = f2bf(w1[c1 * 128 + nn]);
            s[jj] = q0 | (q1 << 16);
        }
        Wp0[e] = make_uint4(r[0], r[1], r[2], r[3]);
        Wp1[e] = make_uint4(s[0], s[1], s[2], s[3]);
    }
    if (b == 0) {
        if (t < nbins) binCur[t] = t * BINCAP;
        for (int i = t; i < 64 * 128; i += 256) pool[i] = 0;
    }
    if (b == 1 && t < 128) {
        int c = ((t & 7) << 4) | (t >> 3);
        b0p[t] = b0[c];
        b1p[t] = b1[c];
    }
}

// ---------------------------------------------------------------- pass1 scatter into strided bins (LDS-grouped runs)
__global__ __launch_bounds__(256) void k_p1scatter(const int* __restrict__ row, const int* __restrict__ col,
                                                   int* __restrict__ binCur, unsigned* __restrict__ ebuf, int E) {
    __shared__ int h[256], s[256], delta[256], lcur[256];
    __shared__ unsigned stage[4096];
    int t = threadIdx.x;
    h[t] = 0;
    __syncthreads();
    int base = blockIdx.x * 4096;
    int cnt = min(4096, E - base);
    if (cnt == 4096) {
        int myc[16], myr[16];
        const int4* c4 = (const int4*)(col + base);
        const int4* r4 = (const int4*)(row + base);
#pragma unroll
        for (int k = 0; k < 4; ++k) {
            int4 cv = c4[t * 4 + k];
            int4 rv = r4[t * 4 + k];
            myc[k * 4 + 0] = cv.x; myc[k * 4 + 1] = cv.y; myc[k * 4 + 2] = cv.z; myc[k * 4 + 3] = cv.w;
            myr[k * 4 + 0] = rv.x; myr[k * 4 + 1] = rv.y; myr[k * 4 + 2] = rv.z; myr[k * 4 + 3] = rv.w;
        }
#pragma unroll
        for (int k = 0; k < 16; ++k) atomicAdd(&h[myc[k] >> 8], 1);
        __syncthreads();
        int v = h[t];
        s[t] = v;
        __syncthreads();
        for (int off = 1; off < 256; off <<= 1) {
            int tmp = (t >= off) ? s[t - off] : 0;
            __syncthreads();
            s[t] += tmp;
            __syncthreads();
        }
        int excl = s[t] - v;
        lcur[t] = excl;
        delta[t] = (v > 0) ? (atomicAdd(&binCur[t], v) - excl) : 0;
        __syncthreads();
#pragma unroll
        for (int k = 0; k < 16; ++k) {
            int d = myc[k];
            int slot = atomicAdd(&lcur[d >> 8], 1);
            stage[slot] = ((unsigned)d << 16) | (unsigned)myr[k];   // n < 2^16: both fit
        }
        __syncthreads();
#pragma unroll
        for (int k = 0; k < 16; ++k) {
            int slot = k * 256 + t;
            unsigned vv = stage[slot];
            int b = vv >> 24;
            ebuf[delta[b] + slot] = vv;
        }
    } else {
        for (int k = 0; k < 16; ++k) {
            int e = base + k * 256 + t;
            if (e < E) atomicAdd(&h[col[e] >> 8], 1);
        }
        __syncthreads();
        int v = h[t];
        s[t] = v;
        __syncthreads();
        for (int off = 1; off < 256; off <<= 1) {
            int tmp = (t >= off) ? s[t - off] : 0;
            __syncthreads();
            s[t] += tmp;
            __syncthreads();
        }
        int excl = s[t] - v;
        lcur[t] = excl;
        delta[t] = (v > 0) ? (atomicAdd(&binCur[t], v) - excl) : 0;
        __syncthreads();
        for (int k = 0; k < 16; ++k) {
            int e = base + k * 256 + t;
            if (e < E) {
                int d = col[e];
                int slot = atomicAdd(&lcur[d >> 8], 1);
                stage[slot] = ((unsigned)d << 16) | (unsigned)row[e];
            }
        }
        __syncthreads();
        for (int k = 0; k < 16; ++k) {
            int slot = k * 256 + t;
            if (slot < cnt) {
                unsigned vv = stage[slot];
                int b = vv >> 24;
                ebuf[delta[b] + slot] = vv;
            }
        }
    }
}

// ---------------------------------------------------------------- pass2: per-bin counting sort -> csr/off/end/dinv
__global__ __launch_bounds__(256) void k_p2sort(const unsigned* __restrict__ ebuf, const int* __restrict__ binCur,
                                                int* __restrict__ csr, int* __restrict__ off_, int* __restrict__ end_,
                                                float* __restrict__ dinv, int n) {
    __shared__ unsigned stage[P2CAP];
    __shared__ unsigned stage2[P2CAP];
    __shared__ int h[256], s[256], cur[256];
    int b = blockIdx.x, t = threadIdx.x;
    int beg = b * BINCAP;
    int cnt = binCur[b] - beg;
    h[t] = 0;
    __syncthreads();
    int nfull = cnt >> 2;
    const uint4* e4 = (const uint4*)(ebuf + beg);   // beg 16B aligned (BINCAP%4==0)
    uint4* st4 = (uint4*)stage;
    for (int i = t; i < nfull; i += 256) {
        uint4 v = e4[i];
        st4[i] = v;
        atomicAdd(&h[(v.x >> 16) & 0xFF], 1);
        atomicAdd(&h[(v.y >> 16) & 0xFF], 1);
        atomicAdd(&h[(v.z >> 16) & 0xFF], 1);
        atomicAdd(&h[(v.w >> 16) & 0xFF], 1);
    }
    for (int i = (nfull << 2) + t; i < cnt; i += 256) {
        unsigned v = ebuf[beg + i];
        stage[i] = v;
        atomicAdd(&h[(v >> 16) & 0xFF], 1);
    }
    __syncthreads();
    int v = h[t];
    s[t] = v;
    __syncthreads();
    for (int off = 1; off < 256; off <<= 1) {
        int tmp = (t >= off) ? s[t - off] : 0;
        __syncthreads();
        s[t] += tmp;
        __syncthreads();
    }
    int excl = s[t] - v;
    cur[t] = excl;
    int d = b * 256 + t;
    if (d < n) {
        off_[d] = beg + excl;
        end_[d] = beg + excl + v;
        dinv[d] = rsqrtf((float)(v + 1));           // +1 self-loop
    }
    __syncthreads();
    for (int i = t; i < cnt; i += 256) {
        unsigned vv = stage[i];
        int slot = atomicAdd(&cur[(vv >> 16) & 0xFF], 1);
        stage2[slot] = vv & 0xFFFFu;
    }
    __syncthreads();
    uint4* c4o = (uint4*)(csr + beg);
    uint4* st24 = (uint4*)stage2;
    for (int i = t; i < nfull; i += 256) c4o[i] = st24[i];
    for (int i = (nfull << 2) + t; i < cnt; i += 256) csr[beg + i] = (int)stage2[i];
}

// ---------------------------------------------------------------- MFMA GEMM, fp32 input (conv0), out bf16 P1 positions
__global__ __launch_bounds__(256) void k_gemm0(const float* __restrict__ x, const uint4* __restrict__ Wp,
                                               const float* __restrict__ dinv, unsigned* __restrict__ outb, int n) {
    int wave = threadIdx.x >> 6, l = threadIdx.x & 63;
    int mt = blockIdx.x * 4 + wave;
    int r0 = mt * 16;
    if (r0 >= n) return;
    int rowA = r0 + (l & 15);
    int kq = (l >> 4) * 8;
    f32x4 acc[8];
#pragma unroll
    for (int U = 0; U < 8; ++U) acc[U] = (f32x4){0.f, 0.f, 0.f, 0.f};
    const float* xr = x + (size_t)rowA * 128 + kq;
#pragma unroll
    for (int T = 0; T < 4; ++T) {
        float4 a0 = *(const float4*)(xr + T * 32);
        float4 a1 = *(const float4*)(xr + T * 32 + 4);
        short8 af;
        af[0] = (short)f2bf(a0.x); af[1] = (short)f2bf(a0.y);
        af[2] = (short)f2bf(a0.z); af[3] = (short)f2bf(a0.w);
        af[4] = (short)f2bf(a1.x); af[5] = (short)f2bf(a1.y);
        af[6] = (short)f2bf(a1.z); af[7] = (short)f2bf(a1.w);
#pragma unroll
        for (int U = 0; U < 8; ++U) {
            short8 bf = *(const short8*)&Wp[(T * 8 + U) * 64 + l];
            acc[U] = __builtin_amdgcn_mfma_f32_16x16x32_bf16(af, bf, acc[U], 0, 0, 0);
        }
    }
    int rq = l >> 4, cl = l & 15;
#pragma unroll
    for (int q = 0; q < 4; ++q) {
        int rr = r0 + rq * 4 + q;
        float d = dinv[rr];
        uint4 w;
        w.x = (unsigned)f2bf(acc[0][q] * d) | ((unsigned)f2bf(acc[1][q] * d) << 16);
        w.y = (unsigned)f2bf(acc[2][q] * d) | ((unsigned)f2bf(acc[3][q] * d) << 16);
        w.z = (unsigned)f2bf(acc[4][q] * d) | ((unsigned)f2bf(acc[5][q] * d) << 16);
        w.w = (unsigned)f2bf(acc[6][q] * d) | ((unsigned)f2bf(acc[7][q] * d) << 16);
        *(uint4*)(outb + (size_t)rr * 64 + cl * 4) = w;
    }
}

// ---------------------------------------------------------------- gather core: wave = 4 nodes, 16 lanes/node, dwordx4
__device__ inline void gather4(const uint4* __restrict__ hp4, const int* __restrict__ csr,
                               int q, int beg, int len, float acc[8]) {
    int maxlen = len;
    maxlen = max(maxlen, __shfl_xor(maxlen, 16, 64));
    maxlen = max(maxlen, __shfl_xor(maxlen, 32, 64));
    int j = 0;
    for (; j + 2 <= maxlen; j += 2) {
        bool a0 = (j < len), a1 = (j + 1 < len);
        int s0 = 0, s1 = 0;
        if (a0) s0 = csr[beg + j];
        if (a1) s1 = csr[beg + j + 1];
        uint4 u0, u1;
        if (a0) u0 = hp4[(size_t)s0 * 16 + q];
        if (a1) u1 = hp4[(size_t)s1 * 16 + q];
        if (a0) {
            acc[0] += bflo(u0.x); acc[1] += bfhi(u0.x);
            acc[2] += bflo(u0.y); acc[3] += bfhi(u0.y);
            acc[4] += bflo(u0.z); acc[5] += bfhi(u0.z);
            acc[6] += bflo(u0.w); acc[7] += bfhi(u0.w);
        }
        if (a1) {
            acc[0] += bflo(u1.x); acc[1] += bfhi(u1.x);
            acc[2] += bflo(u1.y); acc[3] += bfhi(u1.y);
            acc[4] += bflo(u1.z); acc[5] += bfhi(u1.z);
            acc[6] += bflo(u1.w); acc[7] += bfhi(u1.w);
        }
    }
    for (; j < maxlen; ++j) {
        if (j < len) {
            int s0 = csr[beg + j];
            uint4 u = hp4[(size_t)s0 * 16 + q];
            acc[0] += bflo(u.x); acc[1] += bfhi(u.x);
            acc[2] += bflo(u.y); acc[3] += bfhi(u.y);
            acc[4] += bflo(u.z); acc[5] += bfhi(u.z);
            acc[6] += bflo(u.w); acc[7] += bfhi(u.w);
        }
    }
}

// ---------------------------------------------------------------- fused agg(conv0) + GEMM(conv1)
__global__ __launch_bounds__(256) void k_aggemm(const unsigned* __restrict__ hp, const int* __restrict__ off_,
                                                const int* __restrict__ end_, const int* __restrict__ csr,
                                                const float* __restrict__ dinv, const float* __restrict__ bp,
                                                const uint4* __restrict__ Wp, unsigned* __restrict__ outb, int n) {
    __shared__ uint4 sA[16 * 17];
    int w = threadIdx.x >> 6, l = threadIdx.x & 63;
    int g = l >> 4, q = l & 15;
    int r0 = blockIdx.x * 16;
    int node = r0 + w * 4 + g;                  // n % 16 == 0
    const uint4* hp4 = (const uint4*)hp;
    float acc[8];
    uint4 us = hp4[(size_t)node * 16 + q];      // self-loop
    acc[0] = bflo(us.x); acc[1] = bfhi(us.x);
    acc[2] = bflo(us.y); acc[3] = bfhi(us.y);
    acc[4] = bflo(us.z); acc[5] = bfhi(us.z);
    acc[6] = bflo(us.w); acc[7] = bfhi(us.w);
    int beg = off_[node];
    int len = end_[node] - beg;
    gather4(hp4, csr, q, beg, len, acc);
    float d0 = dinv[node];
    const float4* bp4 = (const float4*)bp;
    float4 ba = bp4[q * 2], bb = bp4[q * 2 + 1];
    uint4 pk;
    pk.x = (unsigned)f2bf(fmaxf(fmaf(d0, acc[0], ba.x), 0.f)) | ((unsigned)f2bf(fmaxf(fmaf(d0, acc[1], ba.y), 0.f)) << 16);
    pk.y = (unsigned)f2bf(fmaxf(fmaf(d0, acc[2], ba.z), 0.f)) | ((unsigned)f2bf(fmaxf(fmaf(d0, acc[3], ba.w), 0.f)) << 16);
    pk.z = (unsigned)f2bf(fmaxf(fmaf(d0, acc[4], bb.x), 0.f)) | ((unsigned)f2bf(fmaxf(fmaf(d0, acc[5], bb.y), 0.f)) << 16);
    pk.w = (unsigned)f2bf(fmaxf(fmaf(d0, acc[6], bb.z), 0.f)) | ((unsigned)f2bf(fmaxf(fmaf(d0, acc[7], bb.w), 0.f)) << 16);
    sA[(w * 4 + g) * 17 + q] = pk;
    __syncthreads();
    int rq = l >> 4, cl = l & 15;
    f32x4 c0v = (f32x4){0.f, 0.f, 0.f, 0.f}, c1v = (f32x4){0.f, 0.f, 0.f, 0.f};
#pragma unroll
    for (int T = 0; T < 4; ++T) {
        short8 af = *(const short8*)&sA[(l & 15) * 17 + T * 4 + rq];
        short8 bf0 = *(const short8*)&Wp[(T * 8 + 2 * w) * 64 + l];
        short8 bf1 = *(const short8*)&Wp[(T * 8 + 2 * w + 1) * 64 + l];
        c0v = __builtin_amdgcn_mfma_f32_16x16x32_bf16(af, bf0, c0v, 0, 0, 0);
        c1v = __builtin_amdgcn_mfma_f32_16x16x32_bf16(af, bf1, c1v, 0, 0, 0);
    }
#pragma unroll
    for (int qq = 0; qq < 4; ++qq) {
        int rr = r0 + rq * 4 + qq;
        float d2 = dinv[rr];
        unsigned pkk = (unsigned)f2bf(c0v[qq] * d2) | ((unsigned)f2bf(c1v[qq] * d2) << 16);
        outb[(size_t)rr * 64 + cl * 4 + w] = pkk;
    }
}

// ---------------------------------------------------------------- agg conv1 + fused segment-max pool (16 nodes/block)
__global__ __launch_bounds__(256) void k_agg1(const unsigned* __restrict__ hp, const int* __restrict__ off_,
                                              const int* __restrict__ end_, const int* __restrict__ csr,
                                              const float* __restrict__ dinv, const float* __restrict__ bp,
                                              const int* __restrict__ batch, int* __restrict__ pool, int n) {
    __shared__ float2 sv[16][64];
    __shared__ int sg[16];
    int w = threadIdx.x >> 6, l = threadIdx.x & 63;
    int g = l >> 4, q = l & 15;
    int node = blockIdx.x * 16 + w * 4 + g;     // n % 16 == 0
    const uint4* hp4 = (const uint4*)hp;
    float acc[8];
    uint4 us = hp4[(size_t)node * 16 + q];
    acc[0] = bflo(us.x); acc[1] = bfhi(us.x);
    acc[2] = bflo(us.y); acc[3] = bfhi(us.y);
    acc[4] = bflo(us.z); acc[5] = bfhi(us.z);
    acc[6] = bflo(us.w); acc[7] = bfhi(us.w);
    int beg = off_[node];
    int len = end_[node] - beg;
    gather4(hp4, csr, q, beg, len, acc);
    float d0 = dinv[node];
    const float4* bp4 = (const float4*)bp;
    float4 ba = bp4[q * 2], bb = bp4[q * 2 + 1];
    int rowi = w * 4 + g;
    sv[rowi][q * 4 + 0] = make_float2(fmaxf(fmaf(d0, acc[0], ba.x), 0.f), fmaxf(fmaf(d0, acc[1], ba.y), 0.f));
    sv[rowi][q * 4 + 1] = make_float2(fmaxf(fmaf(d0, acc[2], ba.z), 0.f), fmaxf(fmaf(d0, acc[3], ba.w), 0.f));
    sv[rowi][q * 4 + 2] = make_float2(fmaxf(fmaf(d0, acc[4], bb.x), 0.f), fmaxf(fmaf(d0, acc[5], bb.y), 0.f));
    sv[rowi][q * 4 + 3] = make_float2(fmaxf(fmaf(d0, acc[6], bb.z), 0.f), fmaxf(fmaf(d0, acc[7], bb.w), 0.f));
    if (q == 0) sg[rowi] = batch[node];
    __syncthreads();
    if (threadIdx.x < 64) {
        int t = threadIdx.x;
        int c0 = 32 * (t & 3) + (t >> 2);       // true col of position 2t; pair col = c0+16
        int cur = sg[0];
        float2 m = sv[0][t];
        for (int ww = 1; ww < 16; ++ww) {
            int gg = sg[ww];
            float2 vv = sv[ww][t];
            if (gg == cur) { m.x = fmaxf(m.x, vv.x); m.y = fmaxf(m.y, vv.y); }
            else {
                atomicMax(&pool[cur * 128 + c0], __float_as_int(m.x));
                atomicMax(&pool[cur * 128 + c0 + 16], __float_as_int(m.y));
                cur = gg; m = vv;
            }
        }
        atomicMax(&pool[cur * 128 + c0], __float_as_int(m.x));
        atomicMax(&pool[cur * 128 + c0 + 16], __float_as_int(m.y));
    }
}

// ---------------------------------------------------------------- final MLP + log_softmax, 1 block/graph
__global__ __launch_bounds__(128) void k_mlp(const float* __restrict__ pool, const float* __restrict__ W0,
                                             const float* __restrict__ b0, const float* __restrict__ W1,
                                             const float* __restrict__ b1, float* __restrict__ out) {
    __shared__ float rowv[128];
    __shared__ float h2[128];
    __shared__ float h3[10];
    int g = blockIdx.x, t = threadIdx.x;
    rowv[t] = pool[g * 128 + t];
    __syncthreads();
    float acc = b0[t];
    for (int k = 0; k < 128; ++k) acc = fmaf(rowv[k], W0[k * 128 + t], acc);
    h2[t] = fmaxf(acc, 0.f);
    __syncthreads();
    if (t < 10) {
        float a = b1[t];
        for (int k = 0; k < 128; ++k) a = fmaf(h2[k], W1[k * 10 + t], a);
        h3[t] = fmaxf(a, 0.f);
    }
    __syncthreads();
    if (t == 0) {
        float mx = h3[0];
        for (int j = 1; j < 10; ++j) mx = fmaxf(mx, h3[j]);
        float s = 0.f;
        for (int j = 0; j < 10; ++j) s += expf(h3[j] - mx);
        float lse = logf(s) + mx;
        for (int j = 0; j < 10; ++j) out[g * 10 + j] = h3[j] - lse;
    }
}

// ----------------------------------------------------------------
extern "C" void kernel_launch(void* const* d_in, const int* in_sizes, int n_in,
                              void* d_out, int out_size, void* d_ws, size_t ws_size,
                              hipStream_t stream) {
    const float* x   = (const float*)d_in[0];
    const int* eidx  = (const int*)d_in[1];
    const int* batch = (const int*)d_in[2];
    const float* w0  = (const float*)d_in[3];
    const float* b0  = (const float*)d_in[4];
    const float* w1  = (const float*)d_in[5];
    const float* b1  = (const float*)d_in[6];
    const float* lw0 = (const float*)d_in[7];
    const float* lb0 = (const float*)d_in[8];
    const float* lw1 = (const float*)d_in[9];
    const float* lb1 = (const float*)d_in[10];
    float* out = (float*)d_out;

    int n = in_sizes[2];
    int E = in_sizes[1] / 2;
    const int* row = eidx;        // sources
    const int* col = eidx + E;    // destinations
    int nbins = (n + 255) >> 8;   // 196 (n < 2^16 required for packing)
    int nb1 = (E + 4095) / 4096;

    char* ws = (char*)d_ws;
    size_t o = 0;
    auto take = [&](size_t bytes) { void* p = ws + o; o += (bytes + 255) & ~(size_t)255; return p; };
    int*      binCur   = (int*)     take(256 * 4);
    int*      off_     = (int*)     take((size_t)n * 4);
    int*      end_     = (int*)     take((size_t)n * 4);
    float*    dinv     = (float*)   take((size_t)n * 4);
    int*      csr      = (int*)     take(((size_t)nbins * BINCAP + 64) * 4);
    unsigned* ebuf     = (unsigned*)take(((size_t)nbins * BINCAP + 64) * 4);
    uint4*    Wp0      = (uint4*)   take(2048 * 16);
    uint4*    Wp1      = (uint4*)   take(2048 * 16);
    float*    b0p      = (float*)   take(128 * 4);
    float*    b1p      = (float*)   take(128 * 4);
    unsigned* h0b      = (unsigned*)take((size_t)n * 64 * 4);   // bf16 P1 rows
    unsigned* h1b      = (unsigned*)take((size_t)n * 64 * 4);
    int*      pool     = (int*)     take(64 * 128 * 4);

    k_initW<<<8, 256, 0, stream>>>(w0, w1, b0, b1, Wp0, Wp1, b0p, b1p, binCur, pool, nbins);
    k_p1scatter<<<nb1, 256, 0, stream>>>(row, col, binCur, ebuf, E);
    k_p2sort<<<nbins, 256, 0, stream>>>(ebuf, binCur, csr, off_, end_, dinv, n);

    int mtBlocks = ((n + 15) / 16 + 3) / 4;

    k_gemm0<<<mtBlocks, 256, 0, stream>>>(x, Wp0, dinv, h0b, n);
    k_aggemm<<<n / 16, 256, 0, stream>>>(h0b, off_, end_, csr, dinv, b0p, Wp1, h1b, n);
    k_agg1<<<n / 16, 256, 0, stream>>>(h1b, off_, end_, csr, dinv, b1p, batch, pool, n);
    k_mlp<<<64, 128, 0, stream>>>((const float*)pool, lw0, lb0, lw1, lb1, out);
}